// Round 1
// baseline (310.114 us; speedup 1.0000x reference)
//
#include <hip/hip_runtime.h>
#include <hip/hip_bf16.h>
#include <stdint.h>
#include <math.h>

typedef __attribute__((ext_vector_type(8))) __bf16 bf16x8;
typedef __attribute__((ext_vector_type(4))) float f32x4;

#define B_   32
#define TV_  1024
#define TS_  64
#define DIN_ 1024
#define D_   512

static __device__ __forceinline__ unsigned short f2bf(float f) {
    union { float f; uint32_t u; } x; x.f = f;
    uint32_t r = x.u + 0x7fffu + ((x.u >> 16) & 1u);
    return (unsigned short)(r >> 16);
}

// ---------------- K1: transpose + convert weights: Wt[w][n][k] = W[k][n] (bf16)
__global__ __launch_bounds__(256) void transpose_w(const float* __restrict__ Wv,
                                                   const float* __restrict__ Wsn,
                                                   unsigned short* __restrict__ Wt) {
    const int w = blockIdx.z;
    const float* src = w ? Wsn : Wv;
    __shared__ float t[32][33];
    const int k0 = blockIdx.x * 32, n0 = blockIdx.y * 32;
    const int tx = threadIdx.x & 31, ty = threadIdx.x >> 5;
    #pragma unroll
    for (int r = 0; r < 32; r += 8)
        t[r + ty][tx] = src[(size_t)(k0 + r + ty) * D_ + n0 + tx];
    __syncthreads();
    #pragma unroll
    for (int r = 0; r < 32; r += 8)
        Wt[(size_t)w * 524288 + (size_t)(n0 + r + ty) * DIN_ + k0 + tx] = f2bf(t[tx][r + ty]);
}

// ---------------- K2: encoder GEMM: out[m][n] = bf16( X[m][:] @ W[:][n] + bias[n] )
// X fp32 [M][1024], Wt bf16 [512][1024] (transposed), out bf16 [M][512]
__global__ __launch_bounds__(256) void encoder_gemm(const float* __restrict__ X,
                                                    const unsigned short* __restrict__ Wt,
                                                    const float* __restrict__ bias,
                                                    unsigned short* __restrict__ outR,
                                                    int M) {
    __shared__ char Asb[128 * 128]; // 128 rows x 64 bf16 (128B), XOR-swizzled
    __shared__ char Bsb[128 * 128];
    const int tid = threadIdx.x;
    const int lane = tid & 63, wid = tid >> 6;
    const int g = lane >> 4, c = lane & 15;
    const int wm = wid >> 1, wn = wid & 1;
    const int m0 = blockIdx.x * 128, n0 = blockIdx.y * 128;

    f32x4 acc[4][4];
    {
        f32x4 z = {0.f, 0.f, 0.f, 0.f};
        #pragma unroll
        for (int a = 0; a < 4; ++a)
            #pragma unroll
            for (int b = 0; b < 4; ++b) acc[a][b] = z;
    }

    for (int kk = 0; kk < 16; ++kk) {
        const int k0 = kk * 64;
        // stage A: fp32 -> bf16, swizzled
        #pragma unroll
        for (int it = 0; it < 8; ++it) {
            int idx = it * 256 + tid;
            int m = idx >> 4, k4 = idx & 15;
            float4 v = *(const float4*)(X + (size_t)(m0 + m) * DIN_ + k0 + k4 * 4);
            uint2 pk;
            pk.x = ((uint32_t)f2bf(v.y) << 16) | f2bf(v.x);
            pk.y = ((uint32_t)f2bf(v.w) << 16) | f2bf(v.z);
            *(uint2*)(Asb + m * 128 + ((k4 * 8) ^ ((m & 7) << 4))) = pk;
        }
        // stage B: bf16 copy, swizzled
        #pragma unroll
        for (int it = 0; it < 4; ++it) {
            int idx = it * 256 + tid;
            int n = idx >> 3, kq = idx & 7;
            uint4 v = *(const uint4*)(Wt + (size_t)(n0 + n) * DIN_ + k0 + kq * 8);
            *(uint4*)(Bsb + n * 128 + ((kq * 16) ^ ((n & 7) << 4))) = v;
        }
        __syncthreads();
        #pragma unroll
        for (int ks = 0; ks < 2; ++ks) {
            bf16x8 a[4], b[4];
            #pragma unroll
            for (int mt = 0; mt < 4; ++mt) {
                int row = wm * 64 + mt * 16 + c;
                a[mt] = *(const bf16x8*)(Asb + row * 128 + ((g * 16 + ks * 64) ^ ((c & 7) << 4)));
            }
            #pragma unroll
            for (int nt = 0; nt < 4; ++nt) {
                int rowb = wn * 64 + nt * 16 + c;
                b[nt] = *(const bf16x8*)(Bsb + rowb * 128 + ((g * 16 + ks * 64) ^ ((c & 7) << 4)));
            }
            #pragma unroll
            for (int mt = 0; mt < 4; ++mt)
                #pragma unroll
                for (int nt = 0; nt < 4; ++nt)
                    acc[mt][nt] = __builtin_amdgcn_mfma_f32_16x16x32_bf16(a[mt], b[nt], acc[mt][nt], 0, 0, 0);
        }
        __syncthreads();
    }
    #pragma unroll
    for (int nt = 0; nt < 4; ++nt) {
        int col = n0 + wn * 64 + nt * 16 + c;
        float bb = bias[col];
        #pragma unroll
        for (int mt = 0; mt < 4; ++mt) {
            int rbase = m0 + wm * 64 + mt * 16 + g * 4;
            #pragma unroll
            for (int r = 0; r < 4; ++r)
                outR[(size_t)(rbase + r) * D_ + col] = f2bf(acc[mt][nt][r] + bb);
        }
    }
}

// ---------------- K3: row norms of a bf16 [nrows][512] matrix
__global__ __launch_bounds__(256) void rownorm_kernel(const unsigned short* __restrict__ R,
                                                      float* __restrict__ nrm, int nrows) {
    const int row = blockIdx.x * 4 + (threadIdx.x >> 6);
    const int lane = threadIdx.x & 63;
    if (row >= nrows) return;
    uint4 v = ((const uint4*)(R + (size_t)row * D_))[lane];
    float s = 0.f;
    uint32_t wsx[4] = {v.x, v.y, v.z, v.w};
    #pragma unroll
    for (int q = 0; q < 4; ++q) {
        float lo = __uint_as_float(wsx[q] << 16);
        float hi = __uint_as_float(wsx[q] & 0xffff0000u);
        s += lo * lo + hi * hi;
    }
    #pragma unroll
    for (int d = 1; d < 64; d <<= 1) s += __shfl_xor(s, d);
    if (lane == 0) nrm[row] = sqrtf(s);
}

// ---------------- K4: per-item Gram G = S@S^T (bf16 out) + ns = row norms
__global__ __launch_bounds__(256) void gram_kernel(const unsigned short* __restrict__ S,
                                                   unsigned short* __restrict__ G,
                                                   float* __restrict__ ns) {
    const int i = blockIdx.x;
    const int tid = threadIdx.x, lane = tid & 63, w = tid >> 6;
    const int g = lane >> 4, c = lane & 15;
    const unsigned short* Sp = S + (size_t)i * TS_ * D_;
    f32x4 acc[4];
    {
        f32x4 z = {0.f, 0.f, 0.f, 0.f};
        #pragma unroll
        for (int a = 0; a < 4; ++a) acc[a] = z;
    }
    #pragma unroll
    for (int ks = 0; ks < 16; ++ks) {
        bf16x8 a = *(const bf16x8*)(Sp + (size_t)(w * 16 + c) * D_ + ks * 32 + g * 8);
        #pragma unroll
        for (int nt = 0; nt < 4; ++nt) {
            bf16x8 b = *(const bf16x8*)(Sp + (size_t)(nt * 16 + c) * D_ + ks * 32 + g * 8);
            acc[nt] = __builtin_amdgcn_mfma_f32_16x16x32_bf16(a, b, acc[nt], 0, 0, 0);
        }
    }
    #pragma unroll
    for (int nt = 0; nt < 4; ++nt)
        #pragma unroll
        for (int r = 0; r < 4; ++r) {
            int row = w * 16 + g * 4 + r, col = nt * 16 + c;
            G[(size_t)i * 4096 + row * 64 + col] = f2bf(acc[nt][r]);
        }
    if (tid < 64) {
        const uint4* rp = (const uint4*)(Sp + (size_t)tid * D_);
        float s = 0.f;
        for (int e = 0; e < 64; ++e) {
            uint4 v = rp[e];
            uint32_t wsx[4] = {v.x, v.y, v.z, v.w};
            #pragma unroll
            for (int q = 0; q < 4; ++q) {
                float lo = __uint_as_float(wsx[q] << 16);
                float hi = __uint_as_float(wsx[q] & 0xffff0000u);
                s += lo * lo + hi * hi;
            }
        }
        ns[i * 64 + tid] = sqrtf(s);
    }
}

// ---------------- K5: pairwise co-attention score -> logsumexp, one block per (i,j)
__global__ __launch_bounds__(256) void pairwise_kernel(const unsigned short* __restrict__ V,
                                                       const unsigned short* __restrict__ S,
                                                       const unsigned short* __restrict__ G,
                                                       const float* __restrict__ nv,
                                                       const float* __restrict__ ns,
                                                       float* __restrict__ outp) {
    const int bid = blockIdx.x;
    const int xcd = bid & 7, slot = bid >> 3;
    const int i = xcd + 8 * (slot >> 5);   // same-i blocks land on same XCD (L2 reuse of V_i)
    const int j = slot & 31;
    const int tid = threadIdx.x;
    const int lane = tid & 63, w = tid >> 6;
    const int g = lane >> 4, c = lane & 15;

    __shared__ char Ssh[64 * 1024];   // S_j rows, XOR-swizzled (64KB)
    __shared__ char Psh[4][2048];     // wave-private P tile [16][64] bf16, swizzled
    __shared__ float lse_m[4], lse_s[4];

    // stage S_j into swizzled LDS
    const char* Sj = (const char*)(S + (size_t)j * TS_ * D_);
    #pragma unroll
    for (int it = 0; it < 16; ++it) {
        int idx = it * 256 + tid;
        int row = idx >> 6, ko = (idx & 63) * 16;
        uint4 v = *(const uint4*)(Sj + row * 1024 + ko);
        *(uint4*)(Ssh + row * 1024 + (ko ^ ((row & 7) << 4))) = v;
    }
    // G_j B-fragments held in registers (8 x 16B)
    const unsigned short* Gj = G + (size_t)j * 4096;
    bf16x8 gb[2][4];
    #pragma unroll
    for (int ks = 0; ks < 2; ++ks)
        #pragma unroll
        for (int nt = 0; nt < 4; ++nt)
            gb[ks][nt] = *(const bf16x8*)(Gj + (nt * 16 + c) * 64 + ks * 32 + g * 8);
    float rns[4];
    #pragma unroll
    for (int nt = 0; nt < 4; ++nt) rns[nt] = 1.0f / ns[j * 64 + nt * 16 + c];
    __syncthreads();

    const float L2E = 1.4426950408889634f;
    float m_run = -INFINITY, s_run = 0.0f;
    const unsigned short* Vb = V + ((size_t)i * TV_ + w * 16 + c) * D_ + g * 8;
    const float* nvb = nv + i * TV_ + w * 16 + g * 4;
    char* Pw = Psh[w];

    for (int chunk = 0; chunk < 16; ++chunk) {
        const int rowblk = chunk * 64;
        f32x4 craw[4];
        {
            f32x4 z = {0.f, 0.f, 0.f, 0.f};
            #pragma unroll
            for (int a = 0; a < 4; ++a) craw[a] = z;
        }
        const unsigned short* Vp = Vb + (size_t)rowblk * D_;
        #pragma unroll
        for (int ks = 0; ks < 16; ++ks) {
            bf16x8 a = *(const bf16x8*)(Vp + ks * 32);
            #pragma unroll
            for (int nt = 0; nt < 4; ++nt) {
                int row = nt * 16 + c;
                bf16x8 b = *(const bf16x8*)(Ssh + row * 1024 + ((g * 16 + ks * 64) ^ ((c & 7) << 4)));
                craw[nt] = __builtin_amdgcn_mfma_f32_16x16x32_bf16(a, b, craw[nt], 0, 0, 0);
            }
        }
        float nv4[4], rnv[4];
        #pragma unroll
        for (int r = 0; r < 4; ++r) { nv4[r] = nvb[rowblk + r]; rnv[r] = 1.0f / nv4[r]; }
        float p[4][4], mx[4];
        #pragma unroll
        for (int r = 0; r < 4; ++r) mx[r] = -INFINITY;
        #pragma unroll
        for (int nt = 0; nt < 4; ++nt)
            #pragma unroll
            for (int r = 0; r < 4; ++r) {
                float cn = craw[nt][r] * rnv[r] * rns[nt];
                p[nt][r] = cn;
                mx[r] = fmaxf(mx[r], cn);
            }
        #pragma unroll
        for (int r = 0; r < 4; ++r) {
            mx[r] = fmaxf(mx[r], __shfl_xor(mx[r], 1));
            mx[r] = fmaxf(mx[r], __shfl_xor(mx[r], 2));
            mx[r] = fmaxf(mx[r], __shfl_xor(mx[r], 4));
            mx[r] = fmaxf(mx[r], __shfl_xor(mx[r], 8));
        }
        float Z[4] = {0.f, 0.f, 0.f, 0.f}, SPC[4] = {0.f, 0.f, 0.f, 0.f};
        #pragma unroll
        for (int nt = 0; nt < 4; ++nt)
            #pragma unroll
            for (int r = 0; r < 4; ++r) {
                float e = exp2f((p[nt][r] - mx[r]) * L2E);
                p[nt][r] = e;
                Z[r] += e;
                SPC[r] += e * craw[nt][r];
            }
        #pragma unroll
        for (int r = 0; r < 4; ++r) {
            Z[r] += __shfl_xor(Z[r], 1);  Z[r] += __shfl_xor(Z[r], 2);
            Z[r] += __shfl_xor(Z[r], 4);  Z[r] += __shfl_xor(Z[r], 8);
            SPC[r] += __shfl_xor(SPC[r], 1); SPC[r] += __shfl_xor(SPC[r], 2);
            SPC[r] += __shfl_xor(SPC[r], 4); SPC[r] += __shfl_xor(SPC[r], 8);
        }
        // P -> bf16 via wave-private swizzled LDS (layout change for MFMA A-operand)
        #pragma unroll
        for (int nt = 0; nt < 4; ++nt)
            #pragma unroll
            for (int r = 0; r < 4; ++r) {
                int prow = g * 4 + r;
                int o = (nt * 16 + c) * 2;
                *(unsigned short*)(Pw + prow * 128 + (o ^ ((prow & 7) << 4))) = f2bf(p[nt][r]);
            }
        asm volatile("s_waitcnt lgkmcnt(0)" ::: "memory");
        __builtin_amdgcn_sched_barrier(0);
        f32x4 q[4];
        {
            f32x4 z = {0.f, 0.f, 0.f, 0.f};
            #pragma unroll
            for (int a = 0; a < 4; ++a) q[a] = z;
        }
        #pragma unroll
        for (int ks = 0; ks < 2; ++ks) {
            bf16x8 pa = *(const bf16x8*)(Pw + c * 128 + ((g * 16 + ks * 64) ^ ((c & 7) << 4)));
            #pragma unroll
            for (int nt = 0; nt < 4; ++nt)
                q[nt] = __builtin_amdgcn_mfma_f32_16x16x32_bf16(pa, gb[ks][nt], q[nt], 0, 0, 0);
        }
        float SPQ[4] = {0.f, 0.f, 0.f, 0.f};
        #pragma unroll
        for (int nt = 0; nt < 4; ++nt)
            #pragma unroll
            for (int r = 0; r < 4; ++r) SPQ[r] += p[nt][r] * q[nt][r];
        #pragma unroll
        for (int r = 0; r < 4; ++r) {
            SPQ[r] += __shfl_xor(SPQ[r], 1); SPQ[r] += __shfl_xor(SPQ[r], 2);
            SPQ[r] += __shfl_xor(SPQ[r], 4); SPQ[r] += __shfl_xor(SPQ[r], 8);
        }
        #pragma unroll
        for (int r = 0; r < 4; ++r) {
            float sc = SPC[r] / (nv4[r] * sqrtf(fmaxf(SPQ[r], 0.0f)) + Z[r] * 1e-15f);
            float nm = fmaxf(m_run, sc);
            s_run = s_run * exp2f((m_run - nm) * L2E) + exp2f((sc - nm) * L2E);
            m_run = nm;
        }
    }
    // wave reduce (scores duplicated exactly 16x within wave -> subtract ln(16))
    #pragma unroll
    for (int d = 1; d < 64; d <<= 1) {
        float mo = __shfl_xor(m_run, d);
        float so = __shfl_xor(s_run, d);
        float nm = fmaxf(m_run, mo);
        s_run = s_run * exp2f((m_run - nm) * L2E) + so * exp2f((mo - nm) * L2E);
        m_run = nm;
    }
    if (lane == 0) { lse_m[w] = m_run; lse_s[w] = s_run; }
    __syncthreads();
    if (tid == 0) {
        float m = lse_m[0], s = lse_s[0];
        #pragma unroll
        for (int ww = 1; ww < 4; ++ww) {
            float mo = lse_m[ww], so = lse_s[ww];
            float nm = fmaxf(m, mo);
            s = s * exp2f((m - nm) * L2E) + so * exp2f((mo - nm) * L2E);
            m = nm;
        }
        outp[i * 32 + j] = m + logf(s) - 2.7725887222397812f; // - ln(16)
    }
}

extern "C" void kernel_launch(void* const* d_in, const int* in_sizes, int n_in,
                              void* d_out, int out_size, void* d_ws, size_t ws_size,
                              hipStream_t stream) {
    const float* videos    = (const float*)d_in[0];
    const float* sentences = (const float*)d_in[1];
    // d_in[2] = lengths (unused by the reference computation)
    const float* Wv  = (const float*)d_in[3];
    const float* bv  = (const float*)d_in[4];
    const float* Wsn = (const float*)d_in[5];
    const float* bs  = (const float*)d_in[6];
    float* outp = (float*)d_out;

    char* ws = (char*)d_ws;
    unsigned short* Vrep = (unsigned short*)(ws);                 // 33,554,432 B
    unsigned short* Srep = (unsigned short*)(ws + 33554432);      //  2,097,152 B
    unsigned short* Wt   = (unsigned short*)(ws + 35651584);      //  2,097,152 B
    unsigned short* G    = (unsigned short*)(ws + 37748736);      //    262,144 B
    float*          nv   = (float*)(ws + 38010880);               //    131,072 B
    float*          ns   = (float*)(ws + 38141952);               //      8,192 B

    transpose_w<<<dim3(32, 16, 2), 256, 0, stream>>>(Wv, Wsn, Wt);
    encoder_gemm<<<dim3(256, 4), 256, 0, stream>>>(videos, Wt, bv, Vrep, B_ * TV_);
    encoder_gemm<<<dim3(16, 4), 256, 0, stream>>>(sentences, Wt + 524288, bs, Srep, B_ * TS_);
    rownorm_kernel<<<8192, 256, 0, stream>>>(Vrep, nv, B_ * TV_);
    gram_kernel<<<B_, 256, 0, stream>>>(Srep, G, ns);
    pairwise_kernel<<<1024, 256, 0, stream>>>(Vrep, Srep, G, nv, ns, outp);
}

// Round 2
// 282.378 us; speedup vs baseline: 1.0982x; 1.0982x over previous
//
#include <hip/hip_runtime.h>
#include <hip/hip_bf16.h>
#include <stdint.h>
#include <math.h>

typedef __attribute__((ext_vector_type(8))) __bf16 bf16x8;
typedef __attribute__((ext_vector_type(4))) float f32x4;

#define B_   32
#define TV_  1024
#define TS_  64
#define DIN_ 1024
#define D_   512

static __device__ __forceinline__ unsigned short f2bf(float f) {
    union { float f; uint32_t u; } x; x.f = f;
    uint32_t r = x.u + 0x7fffu + ((x.u >> 16) & 1u);
    return (unsigned short)(r >> 16);
}

// ---------------- K1: transpose + convert weights: Wt[w][n][k] = W[k][n] (bf16)
__global__ __launch_bounds__(256) void transpose_w(const float* __restrict__ Wv,
                                                   const float* __restrict__ Wsn,
                                                   unsigned short* __restrict__ Wt) {
    const int w = blockIdx.z;
    const float* src = w ? Wsn : Wv;
    __shared__ float t[32][33];
    const int k0 = blockIdx.x * 32, n0 = blockIdx.y * 32;
    const int tx = threadIdx.x & 31, ty = threadIdx.x >> 5;
    #pragma unroll
    for (int r = 0; r < 32; r += 8)
        t[r + ty][tx] = src[(size_t)(k0 + r + ty) * D_ + n0 + tx];
    __syncthreads();
    #pragma unroll
    for (int r = 0; r < 32; r += 8)
        Wt[(size_t)w * 524288 + (size_t)(n0 + r + ty) * DIN_ + k0 + tx] = f2bf(t[tx][r + ty]);
}

// ---------------- K2: encoder GEMM: out[m][n] = bf16( X[m][:] @ W[:][n] + bias[n] )
// X fp32 [M][1024], Wt bf16 [512][1024] (transposed), out bf16 [M][512]
// grid: 1-D, XCD-aware: 4 n-blocks of one m-panel run adjacently on one XCD (A-panel L2 reuse)
__global__ __launch_bounds__(256) void encoder_gemm(const float* __restrict__ X,
                                                    const unsigned short* __restrict__ Wt,
                                                    const float* __restrict__ bias,
                                                    unsigned short* __restrict__ outR,
                                                    int mpx) {
    __shared__ char Asb[128 * 128]; // 128 rows x 64 bf16 (128B), XOR-swizzled
    __shared__ char Bsb[128 * 128];
    const int bid = blockIdx.x;
    const int xcd = bid & 7, sl = bid >> 3;
    const int m0 = (xcd * mpx + (sl >> 2)) * 128;
    const int n0 = (sl & 3) * 128;
    const int tid = threadIdx.x;
    const int lane = tid & 63, wid = tid >> 6;
    const int g = lane >> 4, c = lane & 15;
    const int wm = wid >> 1, wn = wid & 1;

    f32x4 acc[4][4];
    {
        f32x4 z = {0.f, 0.f, 0.f, 0.f};
        #pragma unroll
        for (int a = 0; a < 4; ++a)
            #pragma unroll
            for (int b = 0; b < 4; ++b) acc[a][b] = z;
    }

    for (int kk = 0; kk < 16; ++kk) {
        const int k0 = kk * 64;
        #pragma unroll
        for (int it = 0; it < 8; ++it) {
            int idx = it * 256 + tid;
            int m = idx >> 4, k4 = idx & 15;
            float4 v = *(const float4*)(X + (size_t)(m0 + m) * DIN_ + k0 + k4 * 4);
            uint2 pk;
            pk.x = ((uint32_t)f2bf(v.y) << 16) | f2bf(v.x);
            pk.y = ((uint32_t)f2bf(v.w) << 16) | f2bf(v.z);
            *(uint2*)(Asb + m * 128 + ((k4 * 8) ^ ((m & 7) << 4))) = pk;
        }
        #pragma unroll
        for (int it = 0; it < 4; ++it) {
            int idx = it * 256 + tid;
            int n = idx >> 3, kq = idx & 7;
            uint4 v = *(const uint4*)(Wt + (size_t)(n0 + n) * DIN_ + k0 + kq * 8);
            *(uint4*)(Bsb + n * 128 + ((kq * 16) ^ ((n & 7) << 4))) = v;
        }
        __syncthreads();
        #pragma unroll
        for (int ks = 0; ks < 2; ++ks) {
            bf16x8 a[4], b[4];
            #pragma unroll
            for (int mt = 0; mt < 4; ++mt) {
                int row = wm * 64 + mt * 16 + c;
                a[mt] = *(const bf16x8*)(Asb + row * 128 + ((g * 16 + ks * 64) ^ ((c & 7) << 4)));
            }
            #pragma unroll
            for (int nt = 0; nt < 4; ++nt) {
                int rowb = wn * 64 + nt * 16 + c;
                b[nt] = *(const bf16x8*)(Bsb + rowb * 128 + ((g * 16 + ks * 64) ^ ((c & 7) << 4)));
            }
            #pragma unroll
            for (int mt = 0; mt < 4; ++mt)
                #pragma unroll
                for (int nt = 0; nt < 4; ++nt)
                    acc[mt][nt] = __builtin_amdgcn_mfma_f32_16x16x32_bf16(a[mt], b[nt], acc[mt][nt], 0, 0, 0);
        }
        __syncthreads();
    }
    #pragma unroll
    for (int nt = 0; nt < 4; ++nt) {
        int col = n0 + wn * 64 + nt * 16 + c;
        float bb = bias[col];
        #pragma unroll
        for (int mt = 0; mt < 4; ++mt) {
            int rbase = m0 + wm * 64 + mt * 16 + g * 4;
            #pragma unroll
            for (int r = 0; r < 4; ++r)
                outR[(size_t)(rbase + r) * D_ + col] = f2bf(acc[mt][nt][r] + bb);
        }
    }
}

// ---------------- K3: row norms of a bf16 [nrows][512] matrix
__global__ __launch_bounds__(256) void rownorm_kernel(const unsigned short* __restrict__ R,
                                                      float* __restrict__ nrm, int nrows) {
    const int row = blockIdx.x * 4 + (threadIdx.x >> 6);
    const int lane = threadIdx.x & 63;
    if (row >= nrows) return;
    uint4 v = ((const uint4*)(R + (size_t)row * D_))[lane];
    float s = 0.f;
    uint32_t wsx[4] = {v.x, v.y, v.z, v.w};
    #pragma unroll
    for (int q = 0; q < 4; ++q) {
        float lo = __uint_as_float(wsx[q] << 16);
        float hi = __uint_as_float(wsx[q] & 0xffff0000u);
        s += lo * lo + hi * hi;
    }
    #pragma unroll
    for (int d = 1; d < 64; d <<= 1) s += __shfl_xor(s, d);
    if (lane == 0) nrm[row] = sqrtf(s);
}

// ---------------- K4: per-item Gram G = S@S^T (bf16 out) + ns = row norms
__global__ __launch_bounds__(256) void gram_kernel(const unsigned short* __restrict__ S,
                                                   unsigned short* __restrict__ G,
                                                   float* __restrict__ ns) {
    const int i = blockIdx.x;
    const int tid = threadIdx.x, lane = tid & 63, w = tid >> 6;
    const int g = lane >> 4, c = lane & 15;
    const unsigned short* Sp = S + (size_t)i * TS_ * D_;
    f32x4 acc[4];
    {
        f32x4 z = {0.f, 0.f, 0.f, 0.f};
        #pragma unroll
        for (int a = 0; a < 4; ++a) acc[a] = z;
    }
    #pragma unroll
    for (int ks = 0; ks < 16; ++ks) {
        bf16x8 a = *(const bf16x8*)(Sp + (size_t)(w * 16 + c) * D_ + ks * 32 + g * 8);
        #pragma unroll
        for (int nt = 0; nt < 4; ++nt) {
            bf16x8 b = *(const bf16x8*)(Sp + (size_t)(nt * 16 + c) * D_ + ks * 32 + g * 8);
            acc[nt] = __builtin_amdgcn_mfma_f32_16x16x32_bf16(a, b, acc[nt], 0, 0, 0);
        }
    }
    #pragma unroll
    for (int nt = 0; nt < 4; ++nt)
        #pragma unroll
        for (int r = 0; r < 4; ++r) {
            int row = w * 16 + g * 4 + r, col = nt * 16 + c;
            G[(size_t)i * 4096 + row * 64 + col] = f2bf(acc[nt][r]);
        }
    if (tid < 64) {
        const uint4* rp = (const uint4*)(Sp + (size_t)tid * D_);
        float s = 0.f;
        for (int e = 0; e < 64; ++e) {
            uint4 v = rp[e];
            uint32_t wsx[4] = {v.x, v.y, v.z, v.w};
            #pragma unroll
            for (int q = 0; q < 4; ++q) {
                float lo = __uint_as_float(wsx[q] << 16);
                float hi = __uint_as_float(wsx[q] & 0xffff0000u);
                s += lo * lo + hi * hi;
            }
        }
        ns[i * 64 + tid] = sqrtf(s);
    }
}

// ---------------- K5: pairwise co-attention -> logsumexp. One 512-thr block per (i,j).
// Swapped QK^T: D1[s][v] = S·V^T  (A = S frags from LDS frag-order, B = V rows from L2).
// s is lane-local over (at,r); v = col = c. Softmax reduce = in-lane + shfl 16/32.
__global__ __launch_bounds__(512, 2) void pairwise_kernel(const unsigned short* __restrict__ V,
                                                          const unsigned short* __restrict__ S,
                                                          const unsigned short* __restrict__ G,
                                                          const float* __restrict__ nv,
                                                          const float* __restrict__ ns,
                                                          float* __restrict__ outp) {
    __shared__ char Ssh[65536];   // S_j in exact A-frag order: [(ks*4+at)*64 + lane]*16B
    __shared__ char Pl[65536];    // per-wave P tiles [64 v][64 s] bf16, XOR-swizzled
    __shared__ float lsebuf[16];

    const int bid = blockIdx.x;
    const int xcd = bid & 7, slot = bid >> 3;
    const int i = xcd + 8 * (slot >> 5);   // same-i blocks -> same XCD (V_i L2-resident)
    const int j = slot & 31;
    const int tid = threadIdx.x;
    const int lane = tid & 63, w = tid >> 6;
    const int g = lane >> 4, c = lane & 15;
    const int swz = (c & 7) << 4;
    const float L2E = 1.4426950408889634f;

    // ---- stage S_j into frag-order LDS (contiguous writes, 64B-segment reads)
    const char* Sj = (const char*)(S + (size_t)j * TS_ * D_);
    #pragma unroll
    for (int it = 0; it < 8; ++it) {
        int idx = it * 512 + tid;              // 4096 16B-chunks
        int ks = idx >> 8, at = (idx >> 6) & 3, ln = idx & 63;
        int gg = ln >> 4, cc = ln & 15;
        uint4 v = *(const uint4*)(Sj + (at * 16 + cc) * 1024 + ks * 64 + gg * 16);
        *(uint4*)(Ssh + idx * 16) = v;
    }

    // ---- G_j as A-operand frags (registers): G[s'=st*16+c][s=ks2*32+g*8..]
    const unsigned short* Gj = G + (size_t)j * 4096;
    bf16x8 gfr[4][2];
    #pragma unroll
    for (int st = 0; st < 4; ++st)
        #pragma unroll
        for (int ks2 = 0; ks2 < 2; ++ks2)
            gfr[st][ks2] = *(const bf16x8*)(Gj + (st * 16 + c) * 64 + ks2 * 32 + g * 8);

    // ---- 1/ns for the 16 lane-local s values (s = at*16 + g*4 + r)
    float rns[16];
    #pragma unroll
    for (int at = 0; at < 4; ++at) {
        float4 t4 = *(const float4*)(ns + j * 64 + at * 16 + g * 4);
        rns[at * 4 + 0] = __builtin_amdgcn_rcpf(t4.x);
        rns[at * 4 + 1] = __builtin_amdgcn_rcpf(t4.y);
        rns[at * 4 + 2] = __builtin_amdgcn_rcpf(t4.z);
        rns[at * 4 + 3] = __builtin_amdgcn_rcpf(t4.w);
    }
    __syncthreads();

    // per-mt V base pointers: row v = i*1024 + w*64 + mt*16 + c (+ chunk*512), elem k = g*8 (+ks*32)
    const unsigned short* Vb[4];
    #pragma unroll
    for (int mt = 0; mt < 4; ++mt)
        Vb[mt] = V + ((size_t)i * TV_ + w * 64 + mt * 16 + c) * D_ + g * 8;
    const float* nvb = nv + i * TV_ + w * 64 + c;
    char* Plw = Pl + w * 8192;

    float m_run = -INFINITY, s_run = 0.0f;

    for (int chunk = 0; chunk < 2; ++chunk) {
        const int coff = chunk * 512 * D_;   // element offset for +512 rows
        f32x4 acc[4][4];                     // [mt][at] -> D1[s=at*16+g*4+r][v=mt*16+c]
        {
            f32x4 z = {0.f, 0.f, 0.f, 0.f};
            #pragma unroll
            for (int a = 0; a < 4; ++a)
                #pragma unroll
                for (int b = 0; b < 4; ++b) acc[a][b] = z;
        }
        #pragma unroll
        for (int ks = 0; ks < 16; ++ks) {
            bf16x8 a[4], b[4];
            #pragma unroll
            for (int at = 0; at < 4; ++at)
                a[at] = *(const bf16x8*)(Ssh + ((ks * 4 + at) << 10) + lane * 16);
            #pragma unroll
            for (int mt = 0; mt < 4; ++mt)
                b[mt] = *(const bf16x8*)(Vb[mt] + coff + ks * 32);
            #pragma unroll
            for (int mt = 0; mt < 4; ++mt)
                #pragma unroll
                for (int at = 0; at < 4; ++at)
                    acc[mt][at] = __builtin_amdgcn_mfma_f32_16x16x32_bf16(a[at], b[mt], acc[mt][at], 0, 0, 0);
        }

        float Zs[4], SPCs[4], nvs[4];
        // ---- softmax over s (in-lane 16 + shfl 16/32), P -> bf16 packed b64 writes
        #pragma unroll
        for (int mt = 0; mt < 4; ++mt) {
            float nvv = nvb[chunk * 512 + mt * 16];
            float tm = -INFINITY;
            #pragma unroll
            for (int at = 0; at < 4; ++at)
                #pragma unroll
                for (int r = 0; r < 4; ++r)
                    tm = fmaxf(tm, acc[mt][at][r] * rns[at * 4 + r]);
            tm = fmaxf(tm, __shfl_xor(tm, 16));
            tm = fmaxf(tm, __shfl_xor(tm, 32));
            float rnvL = L2E * __builtin_amdgcn_rcpf(nvv);
            float mL = tm * rnvL;
            float Zm = 0.f, SPCm = 0.f;
            #pragma unroll
            for (int at = 0; at < 4; ++at) {
                #pragma unroll
                for (int r = 0; r < 4; ++r) {
                    float t = acc[mt][at][r] * rns[at * 4 + r];
                    float e = exp2f(t * rnvL - mL);
                    Zm += e;
                    SPCm += e * acc[mt][at][r];
                    acc[mt][at][r] = e;     // keep P in regs for the SPQ dot
                }
                uint32_t lo = ((uint32_t)f2bf(acc[mt][at][1]) << 16) | f2bf(acc[mt][at][0]);
                uint32_t hi = ((uint32_t)f2bf(acc[mt][at][3]) << 16) | f2bf(acc[mt][at][2]);
                uint2 pk; pk.x = lo; pk.y = hi;
                *(uint2*)(Plw + (mt * 16 + c) * 128 + ((at * 32 + g * 8) ^ swz)) = pk;
            }
            Zs[mt] = Zm; SPCs[mt] = SPCm; nvs[mt] = nvv;
        }
        asm volatile("s_waitcnt lgkmcnt(0)" ::: "memory");
        __builtin_amdgcn_sched_barrier(0);

        // ---- P@G: D2[s'][v] with A=G, B=P readback; SPQ = in-lane dot + shfl 16/32
        #pragma unroll
        for (int mt = 0; mt < 4; ++mt) {
            bf16x8 b20 = *(const bf16x8*)(Plw + (mt * 16 + c) * 128 + ((g * 16) ^ swz));
            bf16x8 b21 = *(const bf16x8*)(Plw + (mt * 16 + c) * 128 + ((64 + g * 16) ^ swz));
            float SPQ = 0.f;
            #pragma unroll
            for (int st = 0; st < 4; ++st) {
                f32x4 d2 = {0.f, 0.f, 0.f, 0.f};
                d2 = __builtin_amdgcn_mfma_f32_16x16x32_bf16(gfr[st][0], b20, d2, 0, 0, 0);
                d2 = __builtin_amdgcn_mfma_f32_16x16x32_bf16(gfr[st][1], b21, d2, 0, 0, 0);
                #pragma unroll
                for (int r = 0; r < 4; ++r) SPQ += acc[mt][st][r] * d2[r];
            }
            float Zm = Zs[mt], SPCm = SPCs[mt];
            Zm   += __shfl_xor(Zm, 16);   Zm   += __shfl_xor(Zm, 32);
            SPCm += __shfl_xor(SPCm, 16); SPCm += __shfl_xor(SPCm, 32);
            SPQ  += __shfl_xor(SPQ, 16);  SPQ  += __shfl_xor(SPQ, 32);
            float sc = SPCm / (nvs[mt] * sqrtf(fmaxf(SPQ, 0.f)) + Zm * 1e-15f);
            float nm = fmaxf(m_run, sc);
            s_run = s_run * exp2f((m_run - nm) * L2E) + exp2f((sc - nm) * L2E);
            m_run = nm;
        }
    }

    // ---- LSE: reduce over c-lanes (v's are distinct; g-duplicates are identical, not summed)
    #pragma unroll
    for (int d = 1; d < 16; d <<= 1) {
        float mo = __shfl_xor(m_run, d);
        float so = __shfl_xor(s_run, d);
        float nm = fmaxf(m_run, mo);
        s_run = s_run * exp2f((m_run - nm) * L2E) + so * exp2f((mo - nm) * L2E);
        m_run = nm;
    }
    if (lane == 0) { lsebuf[w * 2] = m_run; lsebuf[w * 2 + 1] = s_run; }
    __syncthreads();
    if (tid == 0) {
        float m = lsebuf[0], s = lsebuf[1];
        #pragma unroll
        for (int ww = 1; ww < 8; ++ww) {
            float mo = lsebuf[ww * 2], so = lsebuf[ww * 2 + 1];
            float nm = fmaxf(m, mo);
            s = s * exp2f((m - nm) * L2E) + so * exp2f((mo - nm) * L2E);
            m = nm;
        }
        outp[i * 32 + j] = m + logf(s);
    }
}

extern "C" void kernel_launch(void* const* d_in, const int* in_sizes, int n_in,
                              void* d_out, int out_size, void* d_ws, size_t ws_size,
                              hipStream_t stream) {
    const float* videos    = (const float*)d_in[0];
    const float* sentences = (const float*)d_in[1];
    // d_in[2] = lengths (unused by the reference computation)
    const float* Wv  = (const float*)d_in[3];
    const float* bv  = (const float*)d_in[4];
    const float* Wsn = (const float*)d_in[5];
    const float* bs  = (const float*)d_in[6];
    float* outp = (float*)d_out;

    char* ws = (char*)d_ws;
    unsigned short* Vrep = (unsigned short*)(ws);                 // 33,554,432 B
    unsigned short* Srep = (unsigned short*)(ws + 33554432);      //  2,097,152 B
    unsigned short* Wt   = (unsigned short*)(ws + 35651584);      //  2,097,152 B
    unsigned short* G    = (unsigned short*)(ws + 37748736);      //    262,144 B
    float*          nv   = (float*)(ws + 38010880);               //    131,072 B
    float*          ns   = (float*)(ws + 38141952);               //      8,192 B

    transpose_w<<<dim3(32, 16, 2), 256, 0, stream>>>(Wv, Wsn, Wt);
    encoder_gemm<<<1024, 256, 0, stream>>>(videos, Wt, bv, Vrep, 32);
    encoder_gemm<<<64, 256, 0, stream>>>(sentences, Wt + 524288, bs, Srep, 2);
    rownorm_kernel<<<8192, 256, 0, stream>>>(Vrep, nv, B_ * TV_);
    gram_kernel<<<B_, 256, 0, stream>>>(Srep, G, ns);
    pairwise_kernel<<<1024, 512, 0, stream>>>(Vrep, Srep, G, nv, ns, outp);
}

// Round 3
// 264.639 us; speedup vs baseline: 1.1718x; 1.0670x over previous
//
#include <hip/hip_runtime.h>
#include <hip/hip_bf16.h>
#include <stdint.h>
#include <math.h>

typedef __attribute__((ext_vector_type(8))) __bf16 bf16x8;
typedef __attribute__((ext_vector_type(4))) float f32x4;

#define B_   32
#define TV_  1024
#define TS_  64
#define DIN_ 1024
#define D_   512

static __device__ __forceinline__ unsigned short f2bf(float f) {
    union { float f; uint32_t u; } x; x.f = f;
    uint32_t r = x.u + 0x7fffu + ((x.u >> 16) & 1u);
    return (unsigned short)(r >> 16);
}
static __device__ __forceinline__ uint32_t cvtpk(float lo, float hi) {
    uint32_t r;
    asm("v_cvt_pk_bf16_f32 %0, %1, %2" : "=v"(r) : "v"(lo), "v"(hi));
    return r;
}
static __device__ __forceinline__ void swap32(uint32_t& a, uint32_t& b) {
    asm volatile("v_permlane32_swap_b32 %0, %1" : "+v"(a), "+v"(b));
}
static __device__ __forceinline__ void swap16(uint32_t& a, uint32_t& b) {
    asm volatile("v_permlane16_swap_b32 %0, %1" : "+v"(a), "+v"(b));
}

// ---------------- K1: transpose + convert weights: Wt[w][n][k] = W[k][n] (bf16)
__global__ __launch_bounds__(256) void transpose_w(const float* __restrict__ Wv,
                                                   const float* __restrict__ Wsn,
                                                   unsigned short* __restrict__ Wt) {
    const int w = blockIdx.z;
    const float* src = w ? Wsn : Wv;
    __shared__ float t[32][33];
    const int k0 = blockIdx.x * 32, n0 = blockIdx.y * 32;
    const int tx = threadIdx.x & 31, ty = threadIdx.x >> 5;
    #pragma unroll
    for (int r = 0; r < 32; r += 8)
        t[r + ty][tx] = src[(size_t)(k0 + r + ty) * D_ + n0 + tx];
    __syncthreads();
    #pragma unroll
    for (int r = 0; r < 32; r += 8)
        Wt[(size_t)w * 524288 + (size_t)(n0 + r + ty) * DIN_ + k0 + tx] = f2bf(t[tx][r + ty]);
}

// ---------------- K2: encoder GEMM (unchanged)
__global__ __launch_bounds__(256) void encoder_gemm(const float* __restrict__ X,
                                                    const unsigned short* __restrict__ Wt,
                                                    const float* __restrict__ bias,
                                                    unsigned short* __restrict__ outR,
                                                    int mpx) {
    __shared__ char Asb[128 * 128];
    __shared__ char Bsb[128 * 128];
    const int bid = blockIdx.x;
    const int xcd = bid & 7, sl = bid >> 3;
    const int m0 = (xcd * mpx + (sl >> 2)) * 128;
    const int n0 = (sl & 3) * 128;
    const int tid = threadIdx.x;
    const int lane = tid & 63, wid = tid >> 6;
    const int g = lane >> 4, c = lane & 15;
    const int wm = wid >> 1, wn = wid & 1;

    f32x4 acc[4][4];
    {
        f32x4 z = {0.f, 0.f, 0.f, 0.f};
        #pragma unroll
        for (int a = 0; a < 4; ++a)
            #pragma unroll
            for (int b = 0; b < 4; ++b) acc[a][b] = z;
    }

    for (int kk = 0; kk < 16; ++kk) {
        const int k0 = kk * 64;
        #pragma unroll
        for (int it = 0; it < 8; ++it) {
            int idx = it * 256 + tid;
            int m = idx >> 4, k4 = idx & 15;
            float4 v = *(const float4*)(X + (size_t)(m0 + m) * DIN_ + k0 + k4 * 4);
            uint2 pk;
            pk.x = ((uint32_t)f2bf(v.y) << 16) | f2bf(v.x);
            pk.y = ((uint32_t)f2bf(v.w) << 16) | f2bf(v.z);
            *(uint2*)(Asb + m * 128 + ((k4 * 8) ^ ((m & 7) << 4))) = pk;
        }
        #pragma unroll
        for (int it = 0; it < 4; ++it) {
            int idx = it * 256 + tid;
            int n = idx >> 3, kq = idx & 7;
            uint4 v = *(const uint4*)(Wt + (size_t)(n0 + n) * DIN_ + k0 + kq * 8);
            *(uint4*)(Bsb + n * 128 + ((kq * 16) ^ ((n & 7) << 4))) = v;
        }
        __syncthreads();
        #pragma unroll
        for (int ks = 0; ks < 2; ++ks) {
            bf16x8 a[4], b[4];
            #pragma unroll
            for (int mt = 0; mt < 4; ++mt) {
                int row = wm * 64 + mt * 16 + c;
                a[mt] = *(const bf16x8*)(Asb + row * 128 + ((g * 16 + ks * 64) ^ ((c & 7) << 4)));
            }
            #pragma unroll
            for (int nt = 0; nt < 4; ++nt) {
                int rowb = wn * 64 + nt * 16 + c;
                b[nt] = *(const bf16x8*)(Bsb + rowb * 128 + ((g * 16 + ks * 64) ^ ((c & 7) << 4)));
            }
            #pragma unroll
            for (int mt = 0; mt < 4; ++mt)
                #pragma unroll
                for (int nt = 0; nt < 4; ++nt)
                    acc[mt][nt] = __builtin_amdgcn_mfma_f32_16x16x32_bf16(a[mt], b[nt], acc[mt][nt], 0, 0, 0);
        }
        __syncthreads();
    }
    #pragma unroll
    for (int nt = 0; nt < 4; ++nt) {
        int col = n0 + wn * 64 + nt * 16 + c;
        float bb = bias[col];
        #pragma unroll
        for (int mt = 0; mt < 4; ++mt) {
            int rbase = m0 + wm * 64 + mt * 16 + g * 4;
            #pragma unroll
            for (int r = 0; r < 4; ++r)
                outR[(size_t)(rbase + r) * D_ + col] = f2bf(acc[mt][nt][r] + bb);
        }
    }
}

// ---------------- K3: row norms of bf16 [nrows][512] (video reprs)
__global__ __launch_bounds__(256) void rownorm_kernel(const unsigned short* __restrict__ R,
                                                      float* __restrict__ nrm, int nrows) {
    const int row = blockIdx.x * 4 + (threadIdx.x >> 6);
    const int lane = threadIdx.x & 63;
    if (row >= nrows) return;
    uint4 v = ((const uint4*)(R + (size_t)row * D_))[lane];
    float s = 0.f;
    uint32_t wsx[4] = {v.x, v.y, v.z, v.w};
    #pragma unroll
    for (int q = 0; q < 4; ++q) {
        float lo = __uint_as_float(wsx[q] << 16);
        float hi = __uint_as_float(wsx[q] & 0xffff0000u);
        s += lo * lo + hi * hi;
    }
    #pragma unroll
    for (int d = 1; d < 64; d <<= 1) s += __shfl_xor(s, d);
    if (lane == 0) nrm[row] = sqrtf(s);
}

// ---------------- K4: per-item: ns, lgns=log2(ns); Gn (cosine Gram, frag order, bf16);
//                  Sf = S * (1/ns) in frag order (bf16). One block per item i.
__global__ __launch_bounds__(256) void gram_kernel(const unsigned short* __restrict__ S,
                                                   unsigned short* __restrict__ Gn,
                                                   unsigned short* __restrict__ Sf,
                                                   float* __restrict__ lgns) {
    const int i = blockIdx.x;
    const int tid = threadIdx.x, lane = tid & 63, w = tid >> 6;
    const int g = lane >> 4, c = lane & 15;
    const unsigned short* Sp = S + (size_t)i * TS_ * D_;
    __shared__ float rns_sh[64];

    // phase 1: row sumsq -> ns, lgns, rns
    {
        const int row = tid >> 2, q = tid & 3;
        const uint4* rp = (const uint4*)(Sp + (size_t)row * D_ + q * 128);
        float s = 0.f;
        #pragma unroll
        for (int e = 0; e < 16; ++e) {
            uint4 v = rp[e];
            uint32_t wsx[4] = {v.x, v.y, v.z, v.w};
            #pragma unroll
            for (int qq = 0; qq < 4; ++qq) {
                float lo = __uint_as_float(wsx[qq] << 16);
                float hi = __uint_as_float(wsx[qq] & 0xffff0000u);
                s += lo * lo + hi * hi;
            }
        }
        s += __shfl_xor(s, 1);
        s += __shfl_xor(s, 2);
        if (q == 0) {
            rns_sh[row] = rsqrtf(s);
            lgns[i * 64 + row] = 0.5f * log2f(s);
        }
    }
    __syncthreads();

    // phase 2: Gram via MFMA (raw S), normalize, write frag-order bf16
    {
        f32x4 acc[4];
        {
            f32x4 z = {0.f, 0.f, 0.f, 0.f};
            #pragma unroll
            for (int a = 0; a < 4; ++a) acc[a] = z;
        }
        #pragma unroll
        for (int ks = 0; ks < 16; ++ks) {
            bf16x8 a = *(const bf16x8*)(Sp + (size_t)(w * 16 + c) * D_ + ks * 32 + g * 8);
            #pragma unroll
            for (int nt = 0; nt < 4; ++nt) {
                bf16x8 b = *(const bf16x8*)(Sp + (size_t)(nt * 16 + c) * D_ + ks * 32 + g * 8);
                acc[nt] = __builtin_amdgcn_mfma_f32_16x16x32_bf16(a, b, acc[nt], 0, 0, 0);
            }
        }
        #pragma unroll
        for (int nt = 0; nt < 4; ++nt)
            #pragma unroll
            for (int r = 0; r < 4; ++r) {
                int R = w * 16 + g * 4 + r, C = nt * 16 + c;
                float vn = acc[nt][r] * rns_sh[R] * rns_sh[C];
                int idx = (w * 2 + (nt >> 1)) * 512 + (((nt & 1) * 2 + (c >> 3)) * 16 + g * 4 + r) * 8 + (c & 7);
                Gn[(size_t)i * 4096 + idx] = f2bf(vn);
            }
    }

    // phase 3: normalized S in frag order
    #pragma unroll
    for (int t = 0; t < 16; ++t) {
        int idx = t * 256 + tid;
        int ks = idx >> 8, at = (idx >> 6) & 3, ln = idx & 63;
        int row = at * 16 + (ln & 15), gg = ln >> 4;
        uint4 raw = *(const uint4*)(Sp + (size_t)row * D_ + ks * 32 + gg * 8);
        float sc = rns_sh[row];
        uint32_t rw[4] = {raw.x, raw.y, raw.z, raw.w};
        uint4 o;
        uint32_t* op = (uint32_t*)&o;
        #pragma unroll
        for (int q = 0; q < 4; ++q) {
            float lo = __uint_as_float(rw[q] << 16) * sc;
            float hi = __uint_as_float(rw[q] & 0xffff0000u) * sc;
            op[q] = cvtpk(lo, hi);
        }
        *(uint4*)(Sf + (size_t)i * 32768 + idx * 8) = o;
    }
}

// ---------------- K5: pairwise co-attention -> logsumexp. One 512-thr block per (i,j).
// acc[mt][at] = (V . S_hat^T): s lane-local (at,g,r), v = mt*16+c.
// No softmax max (cosine bounded); ns folded via exponent; P-frags via cvt_pk+permlane.
__global__ __launch_bounds__(512, 4) void pairwise_kernel(const unsigned short* __restrict__ V,
                                                          const unsigned short* __restrict__ Sf,
                                                          const unsigned short* __restrict__ Gn,
                                                          const float* __restrict__ nv,
                                                          const float* __restrict__ lgns,
                                                          float* __restrict__ outp) {
    __shared__ char Ssh[65536];   // normalized S_j, frag order
    __shared__ char Gsh[8192];    // Gn_j, frag order
    __shared__ float wsum[8];

    const int bid = blockIdx.x;
    const int xcd = bid & 7, slot = bid >> 3;
    const int i = xcd + 8 * (slot >> 5);
    const int j = slot & 31;
    const int tid = threadIdx.x;
    const int lane = tid & 63, w = tid >> 6;
    const int g = lane >> 4, c = lane & 15;
    const float L2E = 1.4426950408889634f;

    // stage S_j (pure linear copy) + Gn_j
    {
        const unsigned short* Sjf = Sf + (size_t)j * 32768;
        #pragma unroll
        for (int it = 0; it < 8; ++it) {
            int idx = it * 512 + tid;
            *(uint4*)(Ssh + idx * 16) = *(const uint4*)(Sjf + idx * 8);
        }
        *(uint4*)(Gsh + tid * 16) = *(const uint4*)(Gn + (size_t)j * 4096 + tid * 8);
    }

    // lg[s] for the 16 lane-local s values (s = at*16 + g*4 + r)
    float lg[16];
    #pragma unroll
    for (int at = 0; at < 4; ++at) {
        float4 t4 = *(const float4*)(lgns + j * 64 + at * 16 + g * 4);
        lg[at * 4 + 0] = t4.x; lg[at * 4 + 1] = t4.y;
        lg[at * 4 + 2] = t4.z; lg[at * 4 + 3] = t4.w;
    }
    __syncthreads();

    const unsigned short* Vb[4];
    #pragma unroll
    for (int mt = 0; mt < 4; ++mt)
        Vb[mt] = V + ((size_t)i * TV_ + w * 64 + mt * 16 + c) * D_ + g * 8;
    const float* nvb = nv + i * TV_ + w * 64 + c;

    float s_run = 0.0f;

    for (int chunk = 0; chunk < 2; ++chunk) {
        const size_t coff = (size_t)chunk * 512 * D_;
        f32x4 acc[4][4];   // [mt][at]
        {
            f32x4 z = {0.f, 0.f, 0.f, 0.f};
            #pragma unroll
            for (int a = 0; a < 4; ++a)
                #pragma unroll
                for (int b = 0; b < 4; ++b) acc[a][b] = z;
        }
        #pragma unroll
        for (int ks = 0; ks < 16; ++ks) {
            bf16x8 a[4], b[4];
            #pragma unroll
            for (int at = 0; at < 4; ++at)
                a[at] = *(const bf16x8*)(Ssh + ((ks * 4 + at) << 10) + lane * 16);
            #pragma unroll
            for (int mt = 0; mt < 4; ++mt)
                b[mt] = *(const bf16x8*)(Vb[mt] + coff + ks * 32);
            #pragma unroll
            for (int mt = 0; mt < 4; ++mt)
                #pragma unroll
                for (int at = 0; at < 4; ++at)
                    acc[mt][at] = __builtin_amdgcn_mfma_f32_16x16x32_bf16(a[at], b[mt], acc[mt][at], 0, 0, 0);
        }

        float SPC[4], SPQ[4] = {0.f, 0.f, 0.f, 0.f}, rnv[4];

        #pragma unroll
        for (int half = 0; half < 2; ++half) {
            uint32_t bf[2][2][4];   // [m2][ks2][word]
            #pragma unroll
            for (int m2 = 0; m2 < 2; ++m2) {
                const int mt = half * 2 + m2;
                float nvv = nvb[chunk * 512 + mt * 16];
                float rnv_ = __builtin_amdgcn_rcpf(nvv);
                float rnvL = rnv_ * L2E;
                float SPCm = 0.f;
                #pragma unroll
                for (int at = 0; at < 4; ++at)
                    #pragma unroll
                    for (int r = 0; r < 4; ++r) {
                        float t = acc[mt][at][r];
                        float e = exp2f(fmaf(t, rnvL, lg[at * 4 + r]));
                        SPCm = fmaf(e, t, SPCm);
                        acc[mt][at][r] = e;
                    }
                rnv[mt] = rnv_; SPC[mt] = SPCm;
                #pragma unroll
                for (int ks2 = 0; ks2 < 2; ++ks2) {
                    const int a0 = ks2 * 2, a1 = a0 + 1;
                    uint32_t A  = cvtpk(acc[mt][a0][0], acc[mt][a0][1]);
                    uint32_t Bw = cvtpk(acc[mt][a0][2], acc[mt][a0][3]);
                    uint32_t C  = cvtpk(acc[mt][a1][0], acc[mt][a1][1]);
                    uint32_t Dw = cvtpk(acc[mt][a1][2], acc[mt][a1][3]);
                    swap32(A, C);  swap16(A, C);
                    swap32(Bw, Dw); swap16(Bw, Dw);
                    bf[m2][ks2][0] = A;  bf[m2][ks2][1] = Bw;
                    bf[m2][ks2][2] = C;  bf[m2][ks2][3] = Dw;
                }
            }
            // P@G: A = Gn frags (LDS), B = P-hat frags (regs)
            #pragma unroll
            for (int st = 0; st < 4; ++st) {
                bf16x8 g0 = *(const bf16x8*)(Gsh + ((st * 2 + 0) << 10) + lane * 16);
                bf16x8 g1 = *(const bf16x8*)(Gsh + ((st * 2 + 1) << 10) + lane * 16);
                #pragma unroll
                for (int m2 = 0; m2 < 2; ++m2) {
                    const int mt = half * 2 + m2;
                    union { uint32_t u[4]; bf16x8 v; } f0, f1;
                    #pragma unroll
                    for (int q = 0; q < 4; ++q) { f0.u[q] = bf[m2][0][q]; f1.u[q] = bf[m2][1][q]; }
                    f32x4 d2 = {0.f, 0.f, 0.f, 0.f};
                    d2 = __builtin_amdgcn_mfma_f32_16x16x32_bf16(g0, f0.v, d2, 0, 0, 0);
                    d2 = __builtin_amdgcn_mfma_f32_16x16x32_bf16(g1, f1.v, d2, 0, 0, 0);
                    #pragma unroll
                    for (int r = 0; r < 4; ++r) SPQ[mt] += acc[mt][st][r] * d2[r];
                }
            }
        }

        #pragma unroll
        for (int mt = 0; mt < 4; ++mt) {
            float SPCm = SPC[mt], SPQm = SPQ[mt];
            SPCm += __shfl_xor(SPCm, 16); SPCm += __shfl_xor(SPCm, 32);
            SPQm += __shfl_xor(SPQm, 16); SPQm += __shfl_xor(SPQm, 32);
            float sc = SPCm * rnv[mt] * rsqrtf(fmaxf(SPQm, 1e-20f));
            s_run += exp2f(sc * L2E);
        }
    }

    // sum over c lanes (g-groups hold identical values; take lane 0's group sum)
    #pragma unroll
    for (int d = 1; d < 16; d <<= 1) s_run += __shfl_xor(s_run, d);
    if (lane == 0) wsum[w] = s_run;
    __syncthreads();
    if (tid == 0) {
        float total = 0.f;
        #pragma unroll
        for (int ww = 0; ww < 8; ++ww) total += wsum[ww];
        outp[i * 32 + j] = 0.69314718055994531f * log2f(total);
    }
}

extern "C" void kernel_launch(void* const* d_in, const int* in_sizes, int n_in,
                              void* d_out, int out_size, void* d_ws, size_t ws_size,
                              hipStream_t stream) {
    const float* videos    = (const float*)d_in[0];
    const float* sentences = (const float*)d_in[1];
    // d_in[2] = lengths (unused by the reference computation)
    const float* Wv  = (const float*)d_in[3];
    const float* bv  = (const float*)d_in[4];
    const float* Wsn = (const float*)d_in[5];
    const float* bs  = (const float*)d_in[6];
    float* outp = (float*)d_out;

    char* ws = (char*)d_ws;
    unsigned short* Vrep = (unsigned short*)(ws);                 // 32 MB
    unsigned short* Srep = (unsigned short*)(ws + 33554432);      //  2 MB (raw S repr)
    unsigned short* Wt   = (unsigned short*)(ws + 35651584);      //  2 MB; reused as Sf after encoders
    unsigned short* Gn   = (unsigned short*)(ws + 37748736);      //  256 KB (frag-order cosine Gram)
    float*          nv   = (float*)(ws + 38010880);               //  128 KB
    float*          lgns = (float*)(ws + 38141952);               //  8 KB
    unsigned short* Sf   = Wt;   // alias: Wt dead after encoder_gemm launches complete (stream-ordered)

    transpose_w<<<dim3(32, 16, 2), 256, 0, stream>>>(Wv, Wsn, Wt);
    encoder_gemm<<<1024, 256, 0, stream>>>(videos, Wt, bv, Vrep, 32);
    encoder_gemm<<<64, 256, 0, stream>>>(sentences, Wt + 524288, bs, Srep, 2);
    rownorm_kernel<<<8192, 256, 0, stream>>>(Vrep, nv, B_ * TV_);
    gram_kernel<<<B_, 256, 0, stream>>>(Srep, Gn, Sf, lgns);
    pairwise_kernel<<<1024, 512, 0, stream>>>(Vrep, Sf, Gn, nv, lgns, outp);
}

// Round 4
// 213.977 us; speedup vs baseline: 1.4493x; 1.2368x over previous
//
#include <hip/hip_runtime.h>
#include <hip/hip_bf16.h>
#include <stdint.h>
#include <math.h>

typedef __attribute__((ext_vector_type(8))) __bf16 bf16x8;
typedef __attribute__((ext_vector_type(4))) float f32x4;

#define B_   32
#define TV_  1024
#define TS_  64
#define DIN_ 1024
#define D_   512

static __device__ __forceinline__ unsigned short f2bf(float f) {
    union { float f; uint32_t u; } x; x.f = f;
    uint32_t r = x.u + 0x7fffu + ((x.u >> 16) & 1u);
    return (unsigned short)(r >> 16);
}
static __device__ __forceinline__ uint32_t cvtpk(float lo, float hi) {
    uint32_t r;
    asm("v_cvt_pk_bf16_f32 %0, %1, %2" : "=v"(r) : "v"(lo), "v"(hi));
    return r;
}
static __device__ __forceinline__ void swap32(uint32_t& a, uint32_t& b) {
    asm volatile("v_permlane32_swap_b32 %0, %1" : "+v"(a), "+v"(b));
}
static __device__ __forceinline__ void swap16(uint32_t& a, uint32_t& b) {
    asm volatile("v_permlane16_swap_b32 %0, %1" : "+v"(a), "+v"(b));
}

// ---------------- K1: transpose + convert weights: Wt[w][n][k] = W[k][n] (bf16)
__global__ __launch_bounds__(256) void transpose_w(const float* __restrict__ Wv,
                                                   const float* __restrict__ Wsn,
                                                   unsigned short* __restrict__ Wt) {
    const int w = blockIdx.z;
    const float* src = w ? Wsn : Wv;
    __shared__ float t[32][33];
    const int k0 = blockIdx.x * 32, n0 = blockIdx.y * 32;
    const int tx = threadIdx.x & 31, ty = threadIdx.x >> 5;
    #pragma unroll
    for (int r = 0; r < 32; r += 8)
        t[r + ty][tx] = src[(size_t)(k0 + r + ty) * D_ + n0 + tx];
    __syncthreads();
    #pragma unroll
    for (int r = 0; r < 32; r += 8)
        Wt[(size_t)w * 524288 + (size_t)(n0 + r + ty) * DIN_ + k0 + tx] = f2bf(t[tx][r + ty]);
}

// ---------------- K2: encoder GEMM (unchanged)
__global__ __launch_bounds__(256) void encoder_gemm(const float* __restrict__ X,
                                                    const unsigned short* __restrict__ Wt,
                                                    const float* __restrict__ bias,
                                                    unsigned short* __restrict__ outR,
                                                    int mpx) {
    __shared__ char Asb[128 * 128];
    __shared__ char Bsb[128 * 128];
    const int bid = blockIdx.x;
    const int xcd = bid & 7, sl = bid >> 3;
    const int m0 = (xcd * mpx + (sl >> 2)) * 128;
    const int n0 = (sl & 3) * 128;
    const int tid = threadIdx.x;
    const int lane = tid & 63, wid = tid >> 6;
    const int g = lane >> 4, c = lane & 15;
    const int wm = wid >> 1, wn = wid & 1;

    f32x4 acc[4][4];
    {
        f32x4 z = {0.f, 0.f, 0.f, 0.f};
        #pragma unroll
        for (int a = 0; a < 4; ++a)
            #pragma unroll
            for (int b = 0; b < 4; ++b) acc[a][b] = z;
    }

    for (int kk = 0; kk < 16; ++kk) {
        const int k0 = kk * 64;
        #pragma unroll
        for (int it = 0; it < 8; ++it) {
            int idx = it * 256 + tid;
            int m = idx >> 4, k4 = idx & 15;
            float4 v = *(const float4*)(X + (size_t)(m0 + m) * DIN_ + k0 + k4 * 4);
            uint2 pk;
            pk.x = ((uint32_t)f2bf(v.y) << 16) | f2bf(v.x);
            pk.y = ((uint32_t)f2bf(v.w) << 16) | f2bf(v.z);
            *(uint2*)(Asb + m * 128 + ((k4 * 8) ^ ((m & 7) << 4))) = pk;
        }
        #pragma unroll
        for (int it = 0; it < 4; ++it) {
            int idx = it * 256 + tid;
            int n = idx >> 3, kq = idx & 7;
            uint4 v = *(const uint4*)(Wt + (size_t)(n0 + n) * DIN_ + k0 + kq * 8);
            *(uint4*)(Bsb + n * 128 + ((kq * 16) ^ ((n & 7) << 4))) = v;
        }
        __syncthreads();
        #pragma unroll
        for (int ks = 0; ks < 2; ++ks) {
            bf16x8 a[4], b[4];
            #pragma unroll
            for (int mt = 0; mt < 4; ++mt) {
                int row = wm * 64 + mt * 16 + c;
                a[mt] = *(const bf16x8*)(Asb + row * 128 + ((g * 16 + ks * 64) ^ ((c & 7) << 4)));
            }
            #pragma unroll
            for (int nt = 0; nt < 4; ++nt) {
                int rowb = wn * 64 + nt * 16 + c;
                b[nt] = *(const bf16x8*)(Bsb + rowb * 128 + ((g * 16 + ks * 64) ^ ((c & 7) << 4)));
            }
            #pragma unroll
            for (int mt = 0; mt < 4; ++mt)
                #pragma unroll
                for (int nt = 0; nt < 4; ++nt)
                    acc[mt][nt] = __builtin_amdgcn_mfma_f32_16x16x32_bf16(a[mt], b[nt], acc[mt][nt], 0, 0, 0);
        }
        __syncthreads();
    }
    #pragma unroll
    for (int nt = 0; nt < 4; ++nt) {
        int col = n0 + wn * 64 + nt * 16 + c;
        float bb = bias[col];
        #pragma unroll
        for (int mt = 0; mt < 4; ++mt) {
            int rbase = m0 + wm * 64 + mt * 16 + g * 4;
            #pragma unroll
            for (int r = 0; r < 4; ++r)
                outR[(size_t)(rbase + r) * D_ + col] = f2bf(acc[mt][nt][r] + bb);
        }
    }
}

// ---------------- K3: row norms of bf16 [nrows][512] (video reprs)
__global__ __launch_bounds__(256) void rownorm_kernel(const unsigned short* __restrict__ R,
                                                      float* __restrict__ nrm, int nrows) {
    const int row = blockIdx.x * 4 + (threadIdx.x >> 6);
    const int lane = threadIdx.x & 63;
    if (row >= nrows) return;
    uint4 v = ((const uint4*)(R + (size_t)row * D_))[lane];
    float s = 0.f;
    uint32_t wsx[4] = {v.x, v.y, v.z, v.w};
    #pragma unroll
    for (int q = 0; q < 4; ++q) {
        float lo = __uint_as_float(wsx[q] << 16);
        float hi = __uint_as_float(wsx[q] & 0xffff0000u);
        s += lo * lo + hi * hi;
    }
    #pragma unroll
    for (int d = 1; d < 64; d <<= 1) s += __shfl_xor(s, d);
    if (lane == 0) nrm[row] = sqrtf(s);
}

// ---------------- K4: per-item: lgns=log2(ns); Gn (cosine Gram, frag order, bf16);
//                  Sf = S * (1/ns) in frag order (bf16). One block per item i.
__global__ __launch_bounds__(256) void gram_kernel(const unsigned short* __restrict__ S,
                                                   unsigned short* __restrict__ Gn,
                                                   unsigned short* __restrict__ Sf,
                                                   float* __restrict__ lgns) {
    const int i = blockIdx.x;
    const int tid = threadIdx.x, lane = tid & 63, w = tid >> 6;
    const int g = lane >> 4, c = lane & 15;
    const unsigned short* Sp = S + (size_t)i * TS_ * D_;
    __shared__ float rns_sh[64];

    // phase 1: row sumsq -> lgns, rns
    {
        const int row = tid >> 2, q = tid & 3;
        const uint4* rp = (const uint4*)(Sp + (size_t)row * D_ + q * 128);
        float s = 0.f;
        #pragma unroll
        for (int e = 0; e < 16; ++e) {
            uint4 v = rp[e];
            uint32_t wsx[4] = {v.x, v.y, v.z, v.w};
            #pragma unroll
            for (int qq = 0; qq < 4; ++qq) {
                float lo = __uint_as_float(wsx[qq] << 16);
                float hi = __uint_as_float(wsx[qq] & 0xffff0000u);
                s += lo * lo + hi * hi;
            }
        }
        s += __shfl_xor(s, 1);
        s += __shfl_xor(s, 2);
        if (q == 0) {
            rns_sh[row] = rsqrtf(s);
            lgns[i * 64 + row] = 0.5f * log2f(s);
        }
    }
    __syncthreads();

    // phase 2: Gram via MFMA (raw S), normalize, write frag-order bf16
    {
        f32x4 acc[4];
        {
            f32x4 z = {0.f, 0.f, 0.f, 0.f};
            #pragma unroll
            for (int a = 0; a < 4; ++a) acc[a] = z;
        }
        #pragma unroll
        for (int ks = 0; ks < 16; ++ks) {
            bf16x8 a = *(const bf16x8*)(Sp + (size_t)(w * 16 + c) * D_ + ks * 32 + g * 8);
            #pragma unroll
            for (int nt = 0; nt < 4; ++nt) {
                bf16x8 b = *(const bf16x8*)(Sp + (size_t)(nt * 16 + c) * D_ + ks * 32 + g * 8);
                acc[nt] = __builtin_amdgcn_mfma_f32_16x16x32_bf16(a, b, acc[nt], 0, 0, 0);
            }
        }
        #pragma unroll
        for (int nt = 0; nt < 4; ++nt)
            #pragma unroll
            for (int r = 0; r < 4; ++r) {
                int R = w * 16 + g * 4 + r, C = nt * 16 + c;
                float vn = acc[nt][r] * rns_sh[R] * rns_sh[C];
                int idx = (w * 2 + (nt >> 1)) * 512 + (((nt & 1) * 2 + (c >> 3)) * 16 + g * 4 + r) * 8 + (c & 7);
                Gn[(size_t)i * 4096 + idx] = f2bf(vn);
            }
    }

    // phase 3: normalized S in frag order
    #pragma unroll
    for (int t = 0; t < 16; ++t) {
        int idx = t * 256 + tid;
        int ks = idx >> 8, at = (idx >> 6) & 3, ln = idx & 63;
        int row = at * 16 + (ln & 15), gg = ln >> 4;
        uint4 raw = *(const uint4*)(Sp + (size_t)row * D_ + ks * 32 + gg * 8);
        float sc = rns_sh[row];
        uint32_t rw[4] = {raw.x, raw.y, raw.z, raw.w};
        uint4 o;
        uint32_t* op = (uint32_t*)&o;
        #pragma unroll
        for (int q = 0; q < 4; ++q) {
            float lo = __uint_as_float(rw[q] << 16) * sc;
            float hi = __uint_as_float(rw[q] & 0xffff0000u) * sc;
            op[q] = cvtpk(lo, hi);
        }
        *(uint4*)(Sf + (size_t)i * 32768 + idx * 8) = o;
    }
}

// ---------------- K5: pairwise, TWO j's per block. 512 blocks, 512 threads.
// acc[mt][jj*4+at] = (V . S_hat^T): s lane-local (at,g,r), v = mt*16+c.
__global__ __launch_bounds__(512, 2) void pairwise_kernel(const unsigned short* __restrict__ V,
                                                          const unsigned short* __restrict__ Sf,
                                                          const unsigned short* __restrict__ Gn,
                                                          const float* __restrict__ nv,
                                                          const float* __restrict__ lgns,
                                                          float* __restrict__ outp) {
    __shared__ char Ssh[131072];   // Sf for j0 (64KB) then j1 (64KB), frag order
    __shared__ char Gsh[16384];    // Gn for j0 (8KB), j1 (8KB), frag order
    __shared__ float lgsh[128];    // lgns for j0, j1
    __shared__ float wsum[16];

    const int bid = blockIdx.x;
    const int xcd = bid & 7, slot = bid >> 3;
    const int i = xcd + 8 * (slot >> 4);   // 16 blocks per i, pinned per XCD
    const int jp = slot & 15;              // j = jp*2 + jj
    const int tid = threadIdx.x;
    const int lane = tid & 63, w = tid >> 6;
    const int g = lane >> 4, c = lane & 15;
    const float L2E = 1.4426950408889634f;

    // ---- stage S(2j), G(2j), lg(2j)
    {
        const unsigned short* Sjf = Sf + (size_t)jp * 65536;
        #pragma unroll
        for (int it = 0; it < 16; ++it) {
            int idx = it * 512 + tid;
            *(uint4*)(Ssh + idx * 16) = *(const uint4*)(Sjf + idx * 8);
        }
        const unsigned short* Gp = Gn + (size_t)jp * 8192;
        #pragma unroll
        for (int it = 0; it < 2; ++it) {
            int idx = it * 512 + tid;
            *(uint4*)(Gsh + idx * 16) = *(const uint4*)(Gp + idx * 8);
        }
        if (tid < 32) *(float4*)(lgsh + tid * 4) = *(const float4*)(lgns + jp * 128 + tid * 4);
    }
    __syncthreads();

    const unsigned short* Vb[4];
    #pragma unroll
    for (int mt = 0; mt < 4; ++mt)
        Vb[mt] = V + ((size_t)i * TV_ + w * 64 + mt * 16 + c) * D_ + g * 8;
    const float* nvb = nv + i * TV_ + w * 64 + c;

    float s_run0 = 0.0f, s_run1 = 0.0f;

    for (int chunk = 0; chunk < 2; ++chunk) {
        const size_t coff = (size_t)chunk * 512 * D_;
        f32x4 acc[4][8];   // [mt][jj*4+at]
        {
            f32x4 z = {0.f, 0.f, 0.f, 0.f};
            #pragma unroll
            for (int a = 0; a < 4; ++a)
                #pragma unroll
                for (int b = 0; b < 8; ++b) acc[a][b] = z;
        }
        // explicit V double-buffer over ks
        bf16x8 bcur[4], bnxt[4];
        #pragma unroll
        for (int mt = 0; mt < 4; ++mt) bcur[mt] = *(const bf16x8*)(Vb[mt] + coff);
        #pragma unroll
        for (int ks = 0; ks < 16; ++ks) {
            bf16x8 a[8];
            #pragma unroll
            for (int q = 0; q < 8; ++q)
                a[q] = *(const bf16x8*)(Ssh + ((q >> 2) << 16) + (((ks * 4 + (q & 3))) << 10) + lane * 16);
            if (ks < 15) {
                #pragma unroll
                for (int mt = 0; mt < 4; ++mt)
                    bnxt[mt] = *(const bf16x8*)(Vb[mt] + coff + (ks + 1) * 32);
            }
            #pragma unroll
            for (int mt = 0; mt < 4; ++mt)
                #pragma unroll
                for (int q = 0; q < 8; ++q)
                    acc[mt][q] = __builtin_amdgcn_mfma_f32_16x16x32_bf16(a[q], bcur[mt], acc[mt][q], 0, 0, 0);
            #pragma unroll
            for (int mt = 0; mt < 4; ++mt) bcur[mt] = bnxt[mt];
        }

        float nv4[4], rnv[4];
        #pragma unroll
        for (int mt = 0; mt < 4; ++mt) {
            nv4[mt] = nvb[chunk * 512 + mt * 16];
            rnv[mt] = __builtin_amdgcn_rcpf(nv4[mt]);
        }

        #pragma unroll
        for (int jj = 0; jj < 2; ++jj) {
            float lg[16];
            #pragma unroll
            for (int at = 0; at < 4; ++at) {
                float4 t4 = *(const float4*)(lgsh + jj * 64 + at * 16 + g * 4);
                lg[at * 4 + 0] = t4.x; lg[at * 4 + 1] = t4.y;
                lg[at * 4 + 2] = t4.z; lg[at * 4 + 3] = t4.w;
            }
            float SPC[4], SPQ[4] = {0.f, 0.f, 0.f, 0.f};

            #pragma unroll
            for (int half = 0; half < 2; ++half) {
                uint32_t bfr[2][2][4];   // [m2][ks2][word]
                #pragma unroll
                for (int m2 = 0; m2 < 2; ++m2) {
                    const int mt = half * 2 + m2;
                    float rnvL = rnv[mt] * L2E;
                    float SPCm = 0.f;
                    #pragma unroll
                    for (int at = 0; at < 4; ++at)
                        #pragma unroll
                        for (int r = 0; r < 4; ++r) {
                            float t = acc[mt][jj * 4 + at][r];
                            float e = exp2f(fmaf(t, rnvL, lg[at * 4 + r]));
                            SPCm = fmaf(e, t, SPCm);
                            acc[mt][jj * 4 + at][r] = e;
                        }
                    SPC[mt] = SPCm;
                    #pragma unroll
                    for (int ks2 = 0; ks2 < 2; ++ks2) {
                        const int a0 = jj * 4 + ks2 * 2, a1 = a0 + 1;
                        uint32_t A  = cvtpk(acc[mt][a0][0], acc[mt][a0][1]);
                        uint32_t Bw = cvtpk(acc[mt][a0][2], acc[mt][a0][3]);
                        uint32_t C  = cvtpk(acc[mt][a1][0], acc[mt][a1][1]);
                        uint32_t Dw = cvtpk(acc[mt][a1][2], acc[mt][a1][3]);
                        swap32(A, C);  swap16(A, C);
                        swap32(Bw, Dw); swap16(Bw, Dw);
                        bfr[m2][ks2][0] = A;  bfr[m2][ks2][1] = Bw;
                        bfr[m2][ks2][2] = C;  bfr[m2][ks2][3] = Dw;
                    }
                }
                // P@G: A = Gn frags (LDS), B = P-hat frags (regs)
                #pragma unroll
                for (int st = 0; st < 4; ++st) {
                    bf16x8 g0 = *(const bf16x8*)(Gsh + (jj << 13) + ((st * 2 + 0) << 10) + lane * 16);
                    bf16x8 g1 = *(const bf16x8*)(Gsh + (jj << 13) + ((st * 2 + 1) << 10) + lane * 16);
                    #pragma unroll
                    for (int m2 = 0; m2 < 2; ++m2) {
                        const int mt = half * 2 + m2;
                        union { uint32_t u[4]; bf16x8 v; } f0, f1;
                        #pragma unroll
                        for (int q = 0; q < 4; ++q) { f0.u[q] = bfr[m2][0][q]; f1.u[q] = bfr[m2][1][q]; }
                        f32x4 d2 = {0.f, 0.f, 0.f, 0.f};
                        d2 = __builtin_amdgcn_mfma_f32_16x16x32_bf16(g0, f0.v, d2, 0, 0, 0);
                        d2 = __builtin_amdgcn_mfma_f32_16x16x32_bf16(g1, f1.v, d2, 0, 0, 0);
                        #pragma unroll
                        for (int r = 0; r < 4; ++r) SPQ[mt] += acc[mt][jj * 4 + st][r] * d2[r];
                    }
                }
            }

            #pragma unroll
            for (int mt = 0; mt < 4; ++mt) {
                float SPCm = SPC[mt], SPQm = SPQ[mt];
                SPCm += __shfl_xor(SPCm, 16); SPCm += __shfl_xor(SPCm, 32);
                SPQm += __shfl_xor(SPQm, 16); SPQm += __shfl_xor(SPQm, 32);
                float sc = SPCm * rnv[mt] * rsqrtf(fmaxf(SPQm, 1e-20f));
                float ev = exp2f(sc * L2E);
                if (jj == 0) s_run0 += ev; else s_run1 += ev;
            }
        }
    }

    // sum over c lanes (g-groups hold identical values)
    #pragma unroll
    for (int d = 1; d < 16; d <<= 1) {
        s_run0 += __shfl_xor(s_run0, d);
        s_run1 += __shfl_xor(s_run1, d);
    }
    if (lane == 0) { wsum[w * 2] = s_run0; wsum[w * 2 + 1] = s_run1; }
    __syncthreads();
    if (tid < 2) {
        float total = 0.f;
        #pragma unroll
        for (int ww = 0; ww < 8; ++ww) total += wsum[ww * 2 + tid];
        outp[i * 32 + jp * 2 + tid] = 0.69314718055994531f * log2f(total);
    }
}

extern "C" void kernel_launch(void* const* d_in, const int* in_sizes, int n_in,
                              void* d_out, int out_size, void* d_ws, size_t ws_size,
                              hipStream_t stream) {
    const float* videos    = (const float*)d_in[0];
    const float* sentences = (const float*)d_in[1];
    // d_in[2] = lengths (unused by the reference computation)
    const float* Wv  = (const float*)d_in[3];
    const float* bv  = (const float*)d_in[4];
    const float* Wsn = (const float*)d_in[5];
    const float* bs  = (const float*)d_in[6];
    float* outp = (float*)d_out;

    char* ws = (char*)d_ws;
    unsigned short* Vrep = (unsigned short*)(ws);                 // 32 MB
    unsigned short* Srep = (unsigned short*)(ws + 33554432);      //  2 MB (raw S repr)
    unsigned short* Wt   = (unsigned short*)(ws + 35651584);      //  2 MB; reused as Sf after encoders
    unsigned short* Gn   = (unsigned short*)(ws + 37748736);      //  256 KB (frag-order cosine Gram)
    float*          nv   = (float*)(ws + 38010880);               //  128 KB
    float*          lgns = (float*)(ws + 38141952);               //  8 KB
    unsigned short* Sf   = Wt;   // alias: Wt dead after encoder_gemm launches complete (stream-ordered)

    transpose_w<<<dim3(32, 16, 2), 256, 0, stream>>>(Wv, Wsn, Wt);
    encoder_gemm<<<1024, 256, 0, stream>>>(videos, Wt, bv, Vrep, 32);
    encoder_gemm<<<64, 256, 0, stream>>>(sentences, Wt + 524288, bs, Srep, 2);
    rownorm_kernel<<<8192, 256, 0, stream>>>(Vrep, nv, B_ * TV_);
    gram_kernel<<<B_, 256, 0, stream>>>(Srep, Gn, Sf, lgns);
    pairwise_kernel<<<512, 512, 0, stream>>>(Vrep, Sf, Gn, nv, lgns, outp);
}

// Round 5
// 208.644 us; speedup vs baseline: 1.4863x; 1.0256x over previous
//
#include <hip/hip_runtime.h>
#include <hip/hip_bf16.h>
#include <stdint.h>
#include <math.h>

typedef __attribute__((ext_vector_type(8))) __bf16 bf16x8;
typedef __attribute__((ext_vector_type(4))) float f32x4;

#define B_   32
#define TV_  1024
#define TS_  64
#define DIN_ 1024
#define D_   512

static __device__ __forceinline__ unsigned short f2bf(float f) {
    union { float f; uint32_t u; } x; x.f = f;
    uint32_t r = x.u + 0x7fffu + ((x.u >> 16) & 1u);
    return (unsigned short)(r >> 16);
}
static __device__ __forceinline__ uint32_t cvtpk(float lo, float hi) {
    uint32_t r;
    asm("v_cvt_pk_bf16_f32 %0, %1, %2" : "=v"(r) : "v"(lo), "v"(hi));
    return r;
}
static __device__ __forceinline__ void swap32(uint32_t& a, uint32_t& b) {
    asm volatile("v_permlane32_swap_b32 %0, %1" : "+v"(a), "+v"(b));
}
static __device__ __forceinline__ void swap16(uint32_t& a, uint32_t& b) {
    asm volatile("v_permlane16_swap_b32 %0, %1" : "+v"(a), "+v"(b));
}

// ---------------- K1: transpose + convert weights: Wt[w][n][k] = W[k][n] (bf16)
__global__ __launch_bounds__(256) void transpose_w(const float* __restrict__ Wv,
                                                   const float* __restrict__ Wsn,
                                                   unsigned short* __restrict__ Wt) {
    const int w = blockIdx.z;
    const float* src = w ? Wsn : Wv;
    __shared__ float t[32][33];
    const int k0 = blockIdx.x * 32, n0 = blockIdx.y * 32;
    const int tx = threadIdx.x & 31, ty = threadIdx.x >> 5;
    #pragma unroll
    for (int r = 0; r < 32; r += 8)
        t[r + ty][tx] = src[(size_t)(k0 + r + ty) * D_ + n0 + tx];
    __syncthreads();
    #pragma unroll
    for (int r = 0; r < 32; r += 8)
        Wt[(size_t)w * 524288 + (size_t)(n0 + r + ty) * DIN_ + k0 + tx] = f2bf(t[tx][r + ty]);
}

// ---------------- K2: encoder GEMM (unchanged)
__global__ __launch_bounds__(256) void encoder_gemm(const float* __restrict__ X,
                                                    const unsigned short* __restrict__ Wt,
                                                    const float* __restrict__ bias,
                                                    unsigned short* __restrict__ outR,
                                                    int mpx) {
    __shared__ char Asb[128 * 128];
    __shared__ char Bsb[128 * 128];
    const int bid = blockIdx.x;
    const int xcd = bid & 7, sl = bid >> 3;
    const int m0 = (xcd * mpx + (sl >> 2)) * 128;
    const int n0 = (sl & 3) * 128;
    const int tid = threadIdx.x;
    const int lane = tid & 63, wid = tid >> 6;
    const int g = lane >> 4, c = lane & 15;
    const int wm = wid >> 1, wn = wid & 1;

    f32x4 acc[4][4];
    {
        f32x4 z = {0.f, 0.f, 0.f, 0.f};
        #pragma unroll
        for (int a = 0; a < 4; ++a)
            #pragma unroll
            for (int b = 0; b < 4; ++b) acc[a][b] = z;
    }

    for (int kk = 0; kk < 16; ++kk) {
        const int k0 = kk * 64;
        #pragma unroll
        for (int it = 0; it < 8; ++it) {
            int idx = it * 256 + tid;
            int m = idx >> 4, k4 = idx & 15;
            float4 v = *(const float4*)(X + (size_t)(m0 + m) * DIN_ + k0 + k4 * 4);
            uint2 pk;
            pk.x = ((uint32_t)f2bf(v.y) << 16) | f2bf(v.x);
            pk.y = ((uint32_t)f2bf(v.w) << 16) | f2bf(v.z);
            *(uint2*)(Asb + m * 128 + ((k4 * 8) ^ ((m & 7) << 4))) = pk;
        }
        #pragma unroll
        for (int it = 0; it < 4; ++it) {
            int idx = it * 256 + tid;
            int n = idx >> 3, kq = idx & 7;
            uint4 v = *(const uint4*)(Wt + (size_t)(n0 + n) * DIN_ + k0 + kq * 8);
            *(uint4*)(Bsb + n * 128 + ((kq * 16) ^ ((n & 7) << 4))) = v;
        }
        __syncthreads();
        #pragma unroll
        for (int ks = 0; ks < 2; ++ks) {
            bf16x8 a[4], b[4];
            #pragma unroll
            for (int mt = 0; mt < 4; ++mt) {
                int row = wm * 64 + mt * 16 + c;
                a[mt] = *(const bf16x8*)(Asb + row * 128 + ((g * 16 + ks * 64) ^ ((c & 7) << 4)));
            }
            #pragma unroll
            for (int nt = 0; nt < 4; ++nt) {
                int rowb = wn * 64 + nt * 16 + c;
                b[nt] = *(const bf16x8*)(Bsb + rowb * 128 + ((g * 16 + ks * 64) ^ ((c & 7) << 4)));
            }
            #pragma unroll
            for (int mt = 0; mt < 4; ++mt)
                #pragma unroll
                for (int nt = 0; nt < 4; ++nt)
                    acc[mt][nt] = __builtin_amdgcn_mfma_f32_16x16x32_bf16(a[mt], b[nt], acc[mt][nt], 0, 0, 0);
        }
        __syncthreads();
    }
    #pragma unroll
    for (int nt = 0; nt < 4; ++nt) {
        int col = n0 + wn * 64 + nt * 16 + c;
        float bb = bias[col];
        #pragma unroll
        for (int mt = 0; mt < 4; ++mt) {
            int rbase = m0 + wm * 64 + mt * 16 + g * 4;
            #pragma unroll
            for (int r = 0; r < 4; ++r)
                outR[(size_t)(rbase + r) * D_ + col] = f2bf(acc[mt][nt][r] + bb);
        }
    }
}

// ---------------- K3: row norms of bf16 [nrows][512] (video reprs)
__global__ __launch_bounds__(256) void rownorm_kernel(const unsigned short* __restrict__ R,
                                                      float* __restrict__ nrm, int nrows) {
    const int row = blockIdx.x * 4 + (threadIdx.x >> 6);
    const int lane = threadIdx.x & 63;
    if (row >= nrows) return;
    uint4 v = ((const uint4*)(R + (size_t)row * D_))[lane];
    float s = 0.f;
    uint32_t wsx[4] = {v.x, v.y, v.z, v.w};
    #pragma unroll
    for (int q = 0; q < 4; ++q) {
        float lo = __uint_as_float(wsx[q] << 16);
        float hi = __uint_as_float(wsx[q] & 0xffff0000u);
        s += lo * lo + hi * hi;
    }
    #pragma unroll
    for (int d = 1; d < 64; d <<= 1) s += __shfl_xor(s, d);
    if (lane == 0) nrm[row] = sqrtf(s);
}

// ---------------- K4: per-item: lgns=log2(ns); Gn (cosine Gram, frag order, bf16);
//                  Sf = S * (1/ns) in frag order (bf16). One block per item i.
__global__ __launch_bounds__(256) void gram_kernel(const unsigned short* __restrict__ S,
                                                   unsigned short* __restrict__ Gn,
                                                   unsigned short* __restrict__ Sf,
                                                   float* __restrict__ lgns) {
    const int i = blockIdx.x;
    const int tid = threadIdx.x, lane = tid & 63, w = tid >> 6;
    const int g = lane >> 4, c = lane & 15;
    const unsigned short* Sp = S + (size_t)i * TS_ * D_;
    __shared__ float rns_sh[64];

    // phase 1: row sumsq -> lgns, rns
    {
        const int row = tid >> 2, q = tid & 3;
        const uint4* rp = (const uint4*)(Sp + (size_t)row * D_ + q * 128);
        float s = 0.f;
        #pragma unroll
        for (int e = 0; e < 16; ++e) {
            uint4 v = rp[e];
            uint32_t wsx[4] = {v.x, v.y, v.z, v.w};
            #pragma unroll
            for (int qq = 0; qq < 4; ++qq) {
                float lo = __uint_as_float(wsx[qq] << 16);
                float hi = __uint_as_float(wsx[qq] & 0xffff0000u);
                s += lo * lo + hi * hi;
            }
        }
        s += __shfl_xor(s, 1);
        s += __shfl_xor(s, 2);
        if (q == 0) {
            rns_sh[row] = rsqrtf(s);
            lgns[i * 64 + row] = 0.5f * log2f(s);
        }
    }
    __syncthreads();

    // phase 2: Gram via MFMA (raw S), normalize, write frag-order bf16
    {
        f32x4 acc[4];
        {
            f32x4 z = {0.f, 0.f, 0.f, 0.f};
            #pragma unroll
            for (int a = 0; a < 4; ++a) acc[a] = z;
        }
        #pragma unroll
        for (int ks = 0; ks < 16; ++ks) {
            bf16x8 a = *(const bf16x8*)(Sp + (size_t)(w * 16 + c) * D_ + ks * 32 + g * 8);
            #pragma unroll
            for (int nt = 0; nt < 4; ++nt) {
                bf16x8 b = *(const bf16x8*)(Sp + (size_t)(nt * 16 + c) * D_ + ks * 32 + g * 8);
                acc[nt] = __builtin_amdgcn_mfma_f32_16x16x32_bf16(a, b, acc[nt], 0, 0, 0);
            }
        }
        #pragma unroll
        for (int nt = 0; nt < 4; ++nt)
            #pragma unroll
            for (int r = 0; r < 4; ++r) {
                int R = w * 16 + g * 4 + r, C = nt * 16 + c;
                float vn = acc[nt][r] * rns_sh[R] * rns_sh[C];
                int idx = (w * 2 + (nt >> 1)) * 512 + (((nt & 1) * 2 + (c >> 3)) * 16 + g * 4 + r) * 8 + (c & 7);
                Gn[(size_t)i * 4096 + idx] = f2bf(vn);
            }
    }

    // phase 3: normalized S in frag order
    #pragma unroll
    for (int t = 0; t < 16; ++t) {
        int idx = t * 256 + tid;
        int ks = idx >> 8, at = (idx >> 6) & 3, ln = idx & 63;
        int row = at * 16 + (ln & 15), gg = ln >> 4;
        uint4 raw = *(const uint4*)(Sp + (size_t)row * D_ + ks * 32 + gg * 8);
        float sc = rns_sh[row];
        uint32_t rw[4] = {raw.x, raw.y, raw.z, raw.w};
        uint4 o;
        uint32_t* op = (uint32_t*)&o;
        #pragma unroll
        for (int q = 0; q < 4; ++q) {
            float lo = __uint_as_float(rw[q] << 16) * sc;
            float hi = __uint_as_float(rw[q] & 0xffff0000u) * sc;
            op[q] = cvtpk(lo, hi);
        }
        *(uint4*)(Sf + (size_t)i * 32768 + idx * 8) = o;
    }
}

// ---------------- K5: pairwise, TWO j's per block. 512 blocks, 512 threads.
// acc[mt][jj*4+at] = (V . S_hat^T): s lane-local (at,g,r), v = mt*16+c.
// No min-waves bound: LDS (145KB) already pins 1 block/CU; uncapped regs avoid spills.
__global__ __launch_bounds__(512) void pairwise_kernel(const unsigned short* __restrict__ V,
                                                       const unsigned short* __restrict__ Sf,
                                                       const unsigned short* __restrict__ Gn,
                                                       const float* __restrict__ nv,
                                                       const float* __restrict__ lgns,
                                                       float* __restrict__ outp) {
    __shared__ char Ssh[131072];   // Sf for j0 (64KB) then j1 (64KB), frag order
    __shared__ char Gsh[16384];    // Gn for j0 (8KB), j1 (8KB), frag order
    __shared__ float lgsh[128];    // lgns for j0, j1
    __shared__ float wsum[16];

    const int bid = blockIdx.x;
    const int xcd = bid & 7, slot = bid >> 3;
    const int i = xcd + 8 * (slot >> 4);   // 16 blocks per i, pinned per XCD
    const int jp = slot & 15;              // j = jp*2 + jj
    const int tid = threadIdx.x;
    const int lane = tid & 63, w = tid >> 6;
    const int g = lane >> 4, c = lane & 15;
    const float L2E = 1.4426950408889634f;

    // ---- stage S(2j), G(2j), lg(2j)
    {
        const unsigned short* Sjf = Sf + (size_t)jp * 65536;
        #pragma unroll
        for (int it = 0; it < 16; ++it) {
            int idx = it * 512 + tid;
            *(uint4*)(Ssh + idx * 16) = *(const uint4*)(Sjf + idx * 8);
        }
        const unsigned short* Gp = Gn + (size_t)jp * 8192;
        #pragma unroll
        for (int it = 0; it < 2; ++it) {
            int idx = it * 512 + tid;
            *(uint4*)(Gsh + idx * 16) = *(const uint4*)(Gp + idx * 8);
        }
        if (tid < 32) *(float4*)(lgsh + tid * 4) = *(const float4*)(lgns + jp * 128 + tid * 4);
    }
    __syncthreads();

    const unsigned short* Vb[4];
    #pragma unroll
    for (int mt = 0; mt < 4; ++mt)
        Vb[mt] = V + ((size_t)i * TV_ + w * 64 + mt * 16 + c) * D_ + g * 8;
    const float* nvb = nv + i * TV_ + w * 64 + c;

    float s_run0 = 0.0f, s_run1 = 0.0f;

    for (int chunk = 0; chunk < 2; ++chunk) {
        const size_t coff = (size_t)chunk * 512 * D_;
        f32x4 acc[4][8];   // [mt][jj*4+at]
        {
            f32x4 z = {0.f, 0.f, 0.f, 0.f};
            #pragma unroll
            for (int a = 0; a < 4; ++a)
                #pragma unroll
                for (int b = 0; b < 8; ++b) acc[a][b] = z;
        }
        // explicit V double-buffer over ks
        bf16x8 bcur[4], bnxt[4];
        #pragma unroll
        for (int mt = 0; mt < 4; ++mt) bcur[mt] = *(const bf16x8*)(Vb[mt] + coff);
        #pragma unroll
        for (int ks = 0; ks < 16; ++ks) {
            bf16x8 a[8];
            #pragma unroll
            for (int q = 0; q < 8; ++q)
                a[q] = *(const bf16x8*)(Ssh + ((q >> 2) << 16) + (((ks * 4 + (q & 3))) << 10) + lane * 16);
            if (ks < 15) {
                #pragma unroll
                for (int mt = 0; mt < 4; ++mt)
                    bnxt[mt] = *(const bf16x8*)(Vb[mt] + coff + (ks + 1) * 32);
            }
            __builtin_amdgcn_s_setprio(1);
            #pragma unroll
            for (int mt = 0; mt < 4; ++mt)
                #pragma unroll
                for (int q = 0; q < 8; ++q)
                    acc[mt][q] = __builtin_amdgcn_mfma_f32_16x16x32_bf16(a[q], bcur[mt], acc[mt][q], 0, 0, 0);
            __builtin_amdgcn_s_setprio(0);
            #pragma unroll
            for (int mt = 0; mt < 4; ++mt) bcur[mt] = bnxt[mt];
        }

        float nv4[4], rnv[4];
        #pragma unroll
        for (int mt = 0; mt < 4; ++mt) {
            nv4[mt] = nvb[chunk * 512 + mt * 16];
            rnv[mt] = __builtin_amdgcn_rcpf(nv4[mt]);
        }

        #pragma unroll
        for (int jj = 0; jj < 2; ++jj) {
            float lg[16];
            #pragma unroll
            for (int at = 0; at < 4; ++at) {
                float4 t4 = *(const float4*)(lgsh + jj * 64 + at * 16 + g * 4);
                lg[at * 4 + 0] = t4.x; lg[at * 4 + 1] = t4.y;
                lg[at * 4 + 2] = t4.z; lg[at * 4 + 3] = t4.w;
            }
            float SPC[4], SPQ[4] = {0.f, 0.f, 0.f, 0.f};

            #pragma unroll
            for (int half = 0; half < 2; ++half) {
                uint32_t bfr[2][2][4];   // [m2][ks2][word]
                #pragma unroll
                for (int m2 = 0; m2 < 2; ++m2) {
                    const int mt = half * 2 + m2;
                    float rnvL = rnv[mt] * L2E;
                    float SPCm = 0.f;
                    #pragma unroll
                    for (int at = 0; at < 4; ++at)
                        #pragma unroll
                        for (int r = 0; r < 4; ++r) {
                            float t = acc[mt][jj * 4 + at][r];
                            float e = exp2f(fmaf(t, rnvL, lg[at * 4 + r]));
                            SPCm = fmaf(e, t, SPCm);
                            acc[mt][jj * 4 + at][r] = e;
                        }
                    SPC[mt] = SPCm;
                    #pragma unroll
                    for (int ks2 = 0; ks2 < 2; ++ks2) {
                        const int a0 = jj * 4 + ks2 * 2, a1 = a0 + 1;
                        uint32_t A  = cvtpk(acc[mt][a0][0], acc[mt][a0][1]);
                        uint32_t Bw = cvtpk(acc[mt][a0][2], acc[mt][a0][3]);
                        uint32_t C  = cvtpk(acc[mt][a1][0], acc[mt][a1][1]);
                        uint32_t Dw = cvtpk(acc[mt][a1][2], acc[mt][a1][3]);
                        swap32(A, C);  swap16(A, C);
                        swap32(Bw, Dw); swap16(Bw, Dw);
                        bfr[m2][ks2][0] = A;  bfr[m2][ks2][1] = Bw;
                        bfr[m2][ks2][2] = C;  bfr[m2][ks2][3] = Dw;
                    }
                }
                // P@G: A = Gn frags (LDS), B = P-hat frags (regs)
                #pragma unroll
                for (int st = 0; st < 4; ++st) {
                    bf16x8 g0 = *(const bf16x8*)(Gsh + (jj << 13) + ((st * 2 + 0) << 10) + lane * 16);
                    bf16x8 g1 = *(const bf16x8*)(Gsh + (jj << 13) + ((st * 2 + 1) << 10) + lane * 16);
                    __builtin_amdgcn_s_setprio(1);
                    #pragma unroll
                    for (int m2 = 0; m2 < 2; ++m2) {
                        const int mt = half * 2 + m2;
                        union { uint32_t u[4]; bf16x8 v; } f0, f1;
                        #pragma unroll
                        for (int q = 0; q < 4; ++q) { f0.u[q] = bfr[m2][0][q]; f1.u[q] = bfr[m2][1][q]; }
                        f32x4 d2 = {0.f, 0.f, 0.f, 0.f};
                        d2 = __builtin_amdgcn_mfma_f32_16x16x32_bf16(g0, f0.v, d2, 0, 0, 0);
                        d2 = __builtin_amdgcn_mfma_f32_16x16x32_bf16(g1, f1.v, d2, 0, 0, 0);
                        #pragma unroll
                        for (int r = 0; r < 4; ++r) SPQ[mt] += acc[mt][jj * 4 + st][r] * d2[r];
                    }
                    __builtin_amdgcn_s_setprio(0);
                }
            }

            #pragma unroll
            for (int mt = 0; mt < 4; ++mt) {
                float SPCm = SPC[mt], SPQm = SPQ[mt];
                SPCm += __shfl_xor(SPCm, 16); SPCm += __shfl_xor(SPCm, 32);
                SPQm += __shfl_xor(SPQm, 16); SPQm += __shfl_xor(SPQm, 32);
                float sc = SPCm * rnv[mt] * rsqrtf(fmaxf(SPQm, 1e-20f));
                float ev = exp2f(sc * L2E);
                if (jj == 0) s_run0 += ev; else s_run1 += ev;
            }
        }
    }

    // sum over c lanes (g-groups hold identical values)
    #pragma unroll
    for (int d = 1; d < 16; d <<= 1) {
        s_run0 += __shfl_xor(s_run0, d);
        s_run1 += __shfl_xor(s_run1, d);
    }
    if (lane == 0) { wsum[w * 2] = s_run0; wsum[w * 2 + 1] = s_run1; }
    __syncthreads();
    if (tid < 2) {
        float total = 0.f;
        #pragma unroll
        for (int ww = 0; ww < 8; ++ww) total += wsum[ww * 2 + tid];
        outp[i * 32 + jp * 2 + tid] = 0.69314718055994531f * log2f(total);
    }
}

extern "C" void kernel_launch(void* const* d_in, const int* in_sizes, int n_in,
                              void* d_out, int out_size, void* d_ws, size_t ws_size,
                              hipStream_t stream) {
    const float* videos    = (const float*)d_in[0];
    const float* sentences = (const float*)d_in[1];
    // d_in[2] = lengths (unused by the reference computation)
    const float* Wv  = (const float*)d_in[3];
    const float* bv  = (const float*)d_in[4];
    const float* Wsn = (const float*)d_in[5];
    const float* bs  = (const float*)d_in[6];
    float* outp = (float*)d_out;

    char* ws = (char*)d_ws;
    unsigned short* Vrep = (unsigned short*)(ws);                 // 32 MB
    unsigned short* Srep = (unsigned short*)(ws + 33554432);      //  2 MB (raw S repr)
    unsigned short* Wt   = (unsigned short*)(ws + 35651584);      //  2 MB; reused as Sf after encoders
    unsigned short* Gn   = (unsigned short*)(ws + 37748736);      //  256 KB (frag-order cosine Gram)
    float*          nv   = (float*)(ws + 38010880);               //  128 KB
    float*          lgns = (float*)(ws + 38141952);               //  8 KB
    unsigned short* Sf   = Wt;   // alias: Wt dead after encoder_gemm launches complete (stream-ordered)

    transpose_w<<<dim3(32, 16, 2), 256, 0, stream>>>(Wv, Wsn, Wt);
    encoder_gemm<<<1024, 256, 0, stream>>>(videos, Wt, bv, Vrep, 32);
    encoder_gemm<<<64, 256, 0, stream>>>(sentences, Wt + 524288, bs, Srep, 2);
    rownorm_kernel<<<8192, 256, 0, stream>>>(Vrep, nv, B_ * TV_);
    gram_kernel<<<B_, 256, 0, stream>>>(Srep, Gn, Sf, lgns);
    pairwise_kernel<<<512, 512, 0, stream>>>(Vrep, Sf, Gn, nv, lgns, outp);
}

// Round 6
// 189.167 us; speedup vs baseline: 1.6394x; 1.1030x over previous
//
#include <hip/hip_runtime.h>
#include <hip/hip_bf16.h>
#include <stdint.h>
#include <math.h>

typedef __attribute__((ext_vector_type(8))) __bf16 bf16x8;
typedef __attribute__((ext_vector_type(4))) float f32x4;

#define B_   32
#define TV_  1024
#define TS_  64
#define DIN_ 1024
#define D_   512

static __device__ __forceinline__ unsigned short f2bf(float f) {
    union { float f; uint32_t u; } x; x.f = f;
    uint32_t r = x.u + 0x7fffu + ((x.u >> 16) & 1u);
    return (unsigned short)(r >> 16);
}
static __device__ __forceinline__ uint32_t cvtpk(float lo, float hi) {
    uint32_t r;
    asm("v_cvt_pk_bf16_f32 %0, %1, %2" : "=v"(r) : "v"(lo), "v"(hi));
    return r;
}
static __device__ __forceinline__ void swap32(uint32_t& a, uint32_t& b) {
    asm volatile("v_permlane32_swap_b32 %0, %1" : "+v"(a), "+v"(b));
}
static __device__ __forceinline__ void swap16(uint32_t& a, uint32_t& b) {
    asm volatile("v_permlane16_swap_b32 %0, %1" : "+v"(a), "+v"(b));
}
// async global->LDS, 16B per lane; LDS dest = wave-uniform base + lane*16 (linear)
static __device__ __forceinline__ void gload16(const void* g, void* l) {
    __builtin_amdgcn_global_load_lds((const __attribute__((address_space(1))) uint32_t*)g,
                                     (__attribute__((address_space(3))) uint32_t*)l, 16, 0, 0);
}

// ---------------- K1: transpose + convert weights: Wt[w][n][k] = W[k][n] (bf16)
__global__ __launch_bounds__(256) void transpose_w(const float* __restrict__ Wv,
                                                   const float* __restrict__ Wsn,
                                                   unsigned short* __restrict__ Wt) {
    const int w = blockIdx.z;
    const float* src = w ? Wsn : Wv;
    __shared__ float t[32][33];
    const int k0 = blockIdx.x * 32, n0 = blockIdx.y * 32;
    const int tx = threadIdx.x & 31, ty = threadIdx.x >> 5;
    #pragma unroll
    for (int r = 0; r < 32; r += 8)
        t[r + ty][tx] = src[(size_t)(k0 + r + ty) * D_ + n0 + tx];
    __syncthreads();
    #pragma unroll
    for (int r = 0; r < 32; r += 8)
        Wt[(size_t)w * 524288 + (size_t)(n0 + r + ty) * DIN_ + k0 + tx] = f2bf(t[tx][r + ty]);
}

// ---------------- K2: fused encoder GEMM (video blocks 0..1023, sentence 1024..1087)
// A fp32 reg-staged + swizzled LDS; B bf16 via global_load_lds (linear LDS).
__global__ __launch_bounds__(256) void encoder_gemm(const float* __restrict__ videos,
                                                    const float* __restrict__ sentences,
                                                    const unsigned short* __restrict__ Wt,
                                                    const float* __restrict__ bv,
                                                    const float* __restrict__ bs,
                                                    unsigned short* __restrict__ Vrep,
                                                    unsigned short* __restrict__ Srep) {
    __shared__ char Asb[128 * 128];       // 128 rows x 64 bf16 (128B), XOR-swizzled
    __shared__ char Bsb[128 * 128];       // 128 rows x 64 bf16 (128B), LINEAR (gload_lds)
    const int bid = blockIdx.x;
    const float* X; const unsigned short* W; const float* bias; unsigned short* out;
    int m0, n0;
    if (bid < 1024) {
        int xcd = bid & 7, sl = bid >> 3;
        m0 = (xcd * 32 + (sl >> 2)) * 128;
        n0 = (sl & 3) * 128;
        X = videos; W = Wt; bias = bv; out = Vrep;
    } else {
        int sb = bid - 1024;
        m0 = (sb >> 2) * 128;
        n0 = (sb & 3) * 128;
        X = sentences; W = Wt + 524288; bias = bs; out = Srep;
    }
    const int tid = threadIdx.x;
    const int lane = tid & 63, wid = tid >> 6;
    const int g = lane >> 4, c = lane & 15;
    const int wm = wid >> 1, wn = wid & 1;

    f32x4 acc[4][4];
    {
        f32x4 z = {0.f, 0.f, 0.f, 0.f};
        #pragma unroll
        for (int a = 0; a < 4; ++a)
            #pragma unroll
            for (int b = 0; b < 4; ++b) acc[a][b] = z;
    }

    for (int kk = 0; kk < 16; ++kk) {
        const int k0 = kk * 64;
        // stage A: fp32 -> bf16, swizzled (reg round-trip needed for cvt)
        #pragma unroll
        for (int it = 0; it < 8; ++it) {
            int idx = it * 256 + tid;
            int m = idx >> 4, k4 = idx & 15;
            float4 v = *(const float4*)(X + (size_t)(m0 + m) * DIN_ + k0 + k4 * 4);
            uint2 pk;
            pk.x = cvtpk(v.x, v.y);
            pk.y = cvtpk(v.z, v.w);
            *(uint2*)(Asb + m * 128 + ((k4 * 8) ^ ((m & 7) << 4))) = pk;
        }
        // stage B: async global->LDS, linear layout. 4 calls/wave, rows wid*32+t*8+ln/8
        #pragma unroll
        for (int t = 0; t < 4; ++t) {
            int row = wid * 32 + t * 8 + (lane >> 3);
            const unsigned short* src = W + (size_t)(n0 + row) * DIN_ + k0 + (lane & 7) * 8;
            gload16(src, Bsb + wid * 4096 + t * 1024);
        }
        __syncthreads();
        #pragma unroll
        for (int ks = 0; ks < 2; ++ks) {
            bf16x8 a[4], b[4];
            #pragma unroll
            for (int mt = 0; mt < 4; ++mt) {
                int row = wm * 64 + mt * 16 + c;
                a[mt] = *(const bf16x8*)(Asb + row * 128 + ((g * 16 + ks * 64) ^ ((c & 7) << 4)));
            }
            #pragma unroll
            for (int nt = 0; nt < 4; ++nt) {
                int rowb = wn * 64 + nt * 16 + c;
                b[nt] = *(const bf16x8*)(Bsb + rowb * 128 + (g * 16 + ks * 64));
            }
            #pragma unroll
            for (int mt = 0; mt < 4; ++mt)
                #pragma unroll
                for (int nt = 0; nt < 4; ++nt)
                    acc[mt][nt] = __builtin_amdgcn_mfma_f32_16x16x32_bf16(a[mt], b[nt], acc[mt][nt], 0, 0, 0);
        }
        __syncthreads();
    }
    #pragma unroll
    for (int nt = 0; nt < 4; ++nt) {
        int col = n0 + wn * 64 + nt * 16 + c;
        float bb = bias[col];
        #pragma unroll
        for (int mt = 0; mt < 4; ++mt) {
            int rbase = m0 + wm * 64 + mt * 16 + g * 4;
            #pragma unroll
            for (int r = 0; r < 4; ++r)
                out[(size_t)(rbase + r) * D_ + col] = f2bf(acc[mt][nt][r] + bb);
        }
    }
}

// ---------------- K3: row norms of bf16 [nrows][512] (video reprs)
__global__ __launch_bounds__(256) void rownorm_kernel(const unsigned short* __restrict__ R,
                                                      float* __restrict__ nrm, int nrows) {
    const int row = blockIdx.x * 4 + (threadIdx.x >> 6);
    const int lane = threadIdx.x & 63;
    if (row >= nrows) return;
    uint4 v = ((const uint4*)(R + (size_t)row * D_))[lane];
    float s = 0.f;
    uint32_t wsx[4] = {v.x, v.y, v.z, v.w};
    #pragma unroll
    for (int q = 0; q < 4; ++q) {
        float lo = __uint_as_float(wsx[q] << 16);
        float hi = __uint_as_float(wsx[q] & 0xffff0000u);
        s += lo * lo + hi * hi;
    }
    #pragma unroll
    for (int d = 1; d < 64; d <<= 1) s += __shfl_xor(s, d);
    if (lane == 0) nrm[row] = sqrtf(s);
}

// ---------------- K4: per-item: lgns=log2(ns); Gn (cosine Gram, frag order, bf16);
//                  Sf = S * (1/ns) in frag order (bf16). One block per item i.
__global__ __launch_bounds__(256) void gram_kernel(const unsigned short* __restrict__ S,
                                                   unsigned short* __restrict__ Gn,
                                                   unsigned short* __restrict__ Sf,
                                                   float* __restrict__ lgns) {
    const int i = blockIdx.x;
    const int tid = threadIdx.x, lane = tid & 63, w = tid >> 6;
    const int g = lane >> 4, c = lane & 15;
    const unsigned short* Sp = S + (size_t)i * TS_ * D_;
    __shared__ float rns_sh[64];

    // phase 1: row sumsq -> lgns, rns
    {
        const int row = tid >> 2, q = tid & 3;
        const uint4* rp = (const uint4*)(Sp + (size_t)row * D_ + q * 128);
        float s = 0.f;
        #pragma unroll
        for (int e = 0; e < 16; ++e) {
            uint4 v = rp[e];
            uint32_t wsx[4] = {v.x, v.y, v.z, v.w};
            #pragma unroll
            for (int qq = 0; qq < 4; ++qq) {
                float lo = __uint_as_float(wsx[qq] << 16);
                float hi = __uint_as_float(wsx[qq] & 0xffff0000u);
                s += lo * lo + hi * hi;
            }
        }
        s += __shfl_xor(s, 1);
        s += __shfl_xor(s, 2);
        if (q == 0) {
            rns_sh[row] = rsqrtf(s);
            lgns[i * 64 + row] = 0.5f * log2f(s);
        }
    }
    __syncthreads();

    // phase 2: Gram via MFMA (raw S), normalize, write frag-order bf16
    {
        f32x4 acc[4];
        {
            f32x4 z = {0.f, 0.f, 0.f, 0.f};
            #pragma unroll
            for (int a = 0; a < 4; ++a) acc[a] = z;
        }
        #pragma unroll
        for (int ks = 0; ks < 16; ++ks) {
            bf16x8 a = *(const bf16x8*)(Sp + (size_t)(w * 16 + c) * D_ + ks * 32 + g * 8);
            #pragma unroll
            for (int nt = 0; nt < 4; ++nt) {
                bf16x8 b = *(const bf16x8*)(Sp + (size_t)(nt * 16 + c) * D_ + ks * 32 + g * 8);
                acc[nt] = __builtin_amdgcn_mfma_f32_16x16x32_bf16(a, b, acc[nt], 0, 0, 0);
            }
        }
        #pragma unroll
        for (int nt = 0; nt < 4; ++nt)
            #pragma unroll
            for (int r = 0; r < 4; ++r) {
                int R = w * 16 + g * 4 + r, C = nt * 16 + c;
                float vn = acc[nt][r] * rns_sh[R] * rns_sh[C];
                int idx = (w * 2 + (nt >> 1)) * 512 + (((nt & 1) * 2 + (c >> 3)) * 16 + g * 4 + r) * 8 + (c & 7);
                Gn[(size_t)i * 4096 + idx] = f2bf(vn);
            }
    }

    // phase 3: normalized S in frag order
    #pragma unroll
    for (int t = 0; t < 16; ++t) {
        int idx = t * 256 + tid;
        int ks = idx >> 8, at = (idx >> 6) & 3, ln = idx & 63;
        int row = at * 16 + (ln & 15), gg = ln >> 4;
        uint4 raw = *(const uint4*)(Sp + (size_t)row * D_ + ks * 32 + gg * 8);
        float sc = rns_sh[row];
        uint32_t rw[4] = {raw.x, raw.y, raw.z, raw.w};
        uint4 o;
        uint32_t* op = (uint32_t*)&o;
        #pragma unroll
        for (int q = 0; q < 4; ++q) {
            float lo = __uint_as_float(rw[q] << 16) * sc;
            float hi = __uint_as_float(rw[q] & 0xffff0000u) * sc;
            op[q] = cvtpk(lo, hi);
        }
        *(uint4*)(Sf + (size_t)i * 32768 + idx * 8) = o;
    }
}

// ---------------- K5: pairwise, TWO j's per block, FOUR chunks of 256 v-rows.
// acc[mt][jj*4+at]: mt in {0,1} (32 v-rows/wave/chunk) -> 64 AGPRs, no spills.
__global__ __launch_bounds__(512, 2) void pairwise_kernel(const unsigned short* __restrict__ V,
                                                          const unsigned short* __restrict__ Sf,
                                                          const unsigned short* __restrict__ Gn,
                                                          const float* __restrict__ nv,
                                                          const float* __restrict__ lgns,
                                                          float* __restrict__ outp) {
    __shared__ char Ssh[131072];   // Sf for j0 (64KB) then j1 (64KB), frag order
    __shared__ char Gsh[16384];    // Gn for j0 (8KB), j1 (8KB), frag order
    __shared__ float lgsh[128];    // lgns for j0, j1
    __shared__ float wsum[16];

    const int bid = blockIdx.x;
    const int xcd = bid & 7, slot = bid >> 3;
    const int i = xcd + 8 * (slot >> 4);   // 16 blocks per i, pinned per XCD
    const int jp = slot & 15;              // j = jp*2 + jj
    const int tid = threadIdx.x;
    const int lane = tid & 63, w = tid >> 6;
    const int g = lane >> 4, c = lane & 15;
    const float L2E = 1.4426950408889634f;

    // ---- stage S(2j), G(2j), lg(2j)
    {
        const unsigned short* Sjf = Sf + (size_t)jp * 65536;
        #pragma unroll
        for (int it = 0; it < 16; ++it) {
            int idx = it * 512 + tid;
            *(uint4*)(Ssh + idx * 16) = *(const uint4*)(Sjf + idx * 8);
        }
        const unsigned short* Gp = Gn + (size_t)jp * 8192;
        #pragma unroll
        for (int it = 0; it < 2; ++it) {
            int idx = it * 512 + tid;
            *(uint4*)(Gsh + idx * 16) = *(const uint4*)(Gp + idx * 8);
        }
        if (tid < 32) *(float4*)(lgsh + tid * 4) = *(const float4*)(lgns + jp * 128 + tid * 4);
    }
    __syncthreads();

    const unsigned short* Vb[2];
    #pragma unroll
    for (int mt = 0; mt < 2; ++mt)
        Vb[mt] = V + ((size_t)i * TV_ + w * 32 + mt * 16 + c) * D_ + g * 8;
    const float* nvb = nv + i * TV_ + w * 32 + c;

    float s_run0 = 0.0f, s_run1 = 0.0f;

    for (int chunk = 0; chunk < 4; ++chunk) {
        const size_t coff = (size_t)chunk * 256 * D_;
        f32x4 acc[2][8];   // [mt][jj*4+at]
        {
            f32x4 z = {0.f, 0.f, 0.f, 0.f};
            #pragma unroll
            for (int a = 0; a < 2; ++a)
                #pragma unroll
                for (int b = 0; b < 8; ++b) acc[a][b] = z;
        }
        // explicit V double-buffer over ks
        bf16x8 bcur[2], bnxt[2];
        #pragma unroll
        for (int mt = 0; mt < 2; ++mt) bcur[mt] = *(const bf16x8*)(Vb[mt] + coff);
        #pragma unroll
        for (int ks = 0; ks < 16; ++ks) {
            bf16x8 a[8];
            #pragma unroll
            for (int q = 0; q < 8; ++q)
                a[q] = *(const bf16x8*)(Ssh + ((q >> 2) << 16) + (((ks * 4 + (q & 3))) << 10) + lane * 16);
            if (ks < 15) {
                #pragma unroll
                for (int mt = 0; mt < 2; ++mt)
                    bnxt[mt] = *(const bf16x8*)(Vb[mt] + coff + (ks + 1) * 32);
            }
            __builtin_amdgcn_s_setprio(1);
            #pragma unroll
            for (int mt = 0; mt < 2; ++mt)
                #pragma unroll
                for (int q = 0; q < 8; ++q)
                    acc[mt][q] = __builtin_amdgcn_mfma_f32_16x16x32_bf16(a[q], bcur[mt], acc[mt][q], 0, 0, 0);
            __builtin_amdgcn_s_setprio(0);
            #pragma unroll
            for (int mt = 0; mt < 2; ++mt) bcur[mt] = bnxt[mt];
        }

        float nv4[2], rnv[2];
        #pragma unroll
        for (int mt = 0; mt < 2; ++mt) {
            nv4[mt] = nvb[chunk * 256 + mt * 16];
            rnv[mt] = __builtin_amdgcn_rcpf(nv4[mt]);
        }

        #pragma unroll
        for (int jj = 0; jj < 2; ++jj) {
            float lg[16];
            #pragma unroll
            for (int at = 0; at < 4; ++at) {
                float4 t4 = *(const float4*)(lgsh + jj * 64 + at * 16 + g * 4);
                lg[at * 4 + 0] = t4.x; lg[at * 4 + 1] = t4.y;
                lg[at * 4 + 2] = t4.z; lg[at * 4 + 3] = t4.w;
            }
            float SPC[2], SPQ[2] = {0.f, 0.f};
            uint32_t bfr[2][2][4];   // [mt][ks2][word]
            #pragma unroll
            for (int mt = 0; mt < 2; ++mt) {
                float rnvL = rnv[mt] * L2E;
                float SPCm = 0.f;
                #pragma unroll
                for (int at = 0; at < 4; ++at)
                    #pragma unroll
                    for (int r = 0; r < 4; ++r) {
                        float t = acc[mt][jj * 4 + at][r];
                        float e = exp2f(fmaf(t, rnvL, lg[at * 4 + r]));
                        SPCm = fmaf(e, t, SPCm);
                        acc[mt][jj * 4 + at][r] = e;
                    }
                SPC[mt] = SPCm;
                #pragma unroll
                for (int ks2 = 0; ks2 < 2; ++ks2) {
                    const int a0 = jj * 4 + ks2 * 2, a1 = a0 + 1;
                    uint32_t A  = cvtpk(acc[mt][a0][0], acc[mt][a0][1]);
                    uint32_t Bw = cvtpk(acc[mt][a0][2], acc[mt][a0][3]);
                    uint32_t C  = cvtpk(acc[mt][a1][0], acc[mt][a1][1]);
                    uint32_t Dw = cvtpk(acc[mt][a1][2], acc[mt][a1][3]);
                    swap32(A, C);  swap16(A, C);
                    swap32(Bw, Dw); swap16(Bw, Dw);
                    bfr[mt][ks2][0] = A;  bfr[mt][ks2][1] = Bw;
                    bfr[mt][ks2][2] = C;  bfr[mt][ks2][3] = Dw;
                }
            }
            // P@G: A = Gn frags (LDS), B = P-hat frags (regs)
            #pragma unroll
            for (int st = 0; st < 4; ++st) {
                bf16x8 g0 = *(const bf16x8*)(Gsh + (jj << 13) + ((st * 2 + 0) << 10) + lane * 16);
                bf16x8 g1 = *(const bf16x8*)(Gsh + (jj << 13) + ((st * 2 + 1) << 10) + lane * 16);
                __builtin_amdgcn_s_setprio(1);
                #pragma unroll
                for (int mt = 0; mt < 2; ++mt) {
                    union { uint32_t u[4]; bf16x8 v; } f0, f1;
                    #pragma unroll
                    for (int q = 0; q < 4; ++q) { f0.u[q] = bfr[mt][0][q]; f1.u[q] = bfr[mt][1][q]; }
                    f32x4 d2 = {0.f, 0.f, 0.f, 0.f};
                    d2 = __builtin_amdgcn_mfma_f32_16x16x32_bf16(g0, f0.v, d2, 0, 0, 0);
                    d2 = __builtin_amdgcn_mfma_f32_16x16x32_bf16(g1, f1.v, d2, 0, 0, 0);
                    #pragma unroll
                    for (int r = 0; r < 4; ++r) SPQ[mt] += acc[mt][jj * 4 + st][r] * d2[r];
                }
                __builtin_amdgcn_s_setprio(0);
            }

            #pragma unroll
            for (int mt = 0; mt < 2; ++mt) {
                float SPCm = SPC[mt], SPQm = SPQ[mt];
                SPCm += __shfl_xor(SPCm, 16); SPCm += __shfl_xor(SPCm, 32);
                SPQm += __shfl_xor(SPQm, 16); SPQm += __shfl_xor(SPQm, 32);
                float sc = SPCm * rnv[mt] * rsqrtf(fmaxf(SPQm, 1e-20f));
                float ev = exp2f(sc * L2E);
                if (jj == 0) s_run0 += ev; else s_run1 += ev;
            }
        }
    }

    // sum over c lanes (g-groups hold identical values)
    #pragma unroll
    for (int d = 1; d < 16; d <<= 1) {
        s_run0 += __shfl_xor(s_run0, d);
        s_run1 += __shfl_xor(s_run1, d);
    }
    if (lane == 0) { wsum[w * 2] = s_run0; wsum[w * 2 + 1] = s_run1; }
    __syncthreads();
    if (tid < 2) {
        float total = 0.f;
        #pragma unroll
        for (int ww = 0; ww < 8; ++ww) total += wsum[ww * 2 + tid];
        outp[i * 32 + jp * 2 + tid] = 0.69314718055994531f * log2f(total);
    }
}

extern "C" void kernel_launch(void* const* d_in, const int* in_sizes, int n_in,
                              void* d_out, int out_size, void* d_ws, size_t ws_size,
                              hipStream_t stream) {
    const float* videos    = (const float*)d_in[0];
    const float* sentences = (const float*)d_in[1];
    // d_in[2] = lengths (unused by the reference computation)
    const float* Wv  = (const float*)d_in[3];
    const float* bv  = (const float*)d_in[4];
    const float* Wsn = (const float*)d_in[5];
    const float* bs  = (const float*)d_in[6];
    float* outp = (float*)d_out;

    char* ws = (char*)d_ws;
    unsigned short* Vrep = (unsigned short*)(ws);                 // 32 MB
    unsigned short* Srep = (unsigned short*)(ws + 33554432);      //  2 MB (raw S repr)
    unsigned short* Wt   = (unsigned short*)(ws + 35651584);      //  2 MB; reused as Sf after encoders
    unsigned short* Gn   = (unsigned short*)(ws + 37748736);      //  256 KB (frag-order cosine Gram)
    float*          nv   = (float*)(ws + 38010880);               //  128 KB
    float*          lgns = (float*)(ws + 38141952);               //  8 KB
    unsigned short* Sf   = Wt;   // alias: Wt dead after encoder_gemm completes (stream-ordered)

    transpose_w<<<dim3(32, 16, 2), 256, 0, stream>>>(Wv, Wsn, Wt);
    encoder_gemm<<<1088, 256, 0, stream>>>(videos, sentences, Wt, bv, bs, Vrep, Srep);
    rownorm_kernel<<<8192, 256, 0, stream>>>(Vrep, nv, B_ * TV_);
    gram_kernel<<<B_, 256, 0, stream>>>(Srep, Gn, Sf, lgns);
    pairwise_kernel<<<512, 512, 0, stream>>>(Vrep, Sf, Gn, nv, lgns, outp);
}